// Round 7
// baseline (209.655 us; speedup 1.0000x reference)
//
#include <hip/hip_runtime.h>
#include <math.h>

// Problem constants
#define B_  4
#define C_  256
#define N_  4096
#define CK_ 32
#define CV_ 128

typedef __attribute__((ext_vector_type(8))) short short8;  // 8 bf16 = 4 VGPRs
typedef __attribute__((ext_vector_type(4))) float f32x4;   // MFMA C/D frag
typedef unsigned short u16;
typedef unsigned int   u32;

static constexpr float LOG2E = 1.4426950408889634f;

static __device__ __forceinline__ u16 f2bf(float f) {       // fp32 -> bf16 RNE
    u32 u = __float_as_uint(f);
    u = (u + 0x7FFFu + ((u >> 16) & 1u)) >> 16;
    return (u16)u;
}
static __device__ __forceinline__ float bf2f(u16 h) {
    return __uint_as_float(((u32)h) << 16);
}

// native transcendentals
static __device__ __forceinline__ float fexp2(float x) {
#if __has_builtin(__builtin_amdgcn_exp2f)
    return __builtin_amdgcn_exp2f(x);
#else
    float r; asm("v_exp_f32 %0, %1\n\ts_nop 0" : "=v"(r) : "v"(x)); return r;
#endif
}
static __device__ __forceinline__ float frcp(float x) {
#if __has_builtin(__builtin_amdgcn_rcpf)
    return __builtin_amdgcn_rcpf(x);
#else
    float r; asm("v_rcp_f32 %0, %1\n\ts_nop 0" : "=v"(r) : "v"(x)); return r;
#endif
}
// pack two fp32 -> 2x bf16 (RNE), lo = a, hi = b
static __device__ __forceinline__ u32 cvt_pk_bf16(float a, float b) {
    u32 r; asm("v_cvt_pk_bf16_f32 %0, %1, %2" : "=v"(r) : "v"(a), "v"(b));
    return r;
}

// ---------------------------------------------------------------------------
// Kernel 0: prep = x transpose/convert  +  weight convert (merged).
// ---------------------------------------------------------------------------
__global__ __launch_bounds__(256) void prep_kernel(
    const float* __restrict__ x, u16* __restrict__ xT16,
    const float* __restrict__ theta_w, const float* __restrict__ phi_w,
    const float* __restrict__ g_w,     const float* __restrict__ o_w,
    u16* __restrict__ W16, u16* __restrict__ ow16)
{
    if (blockIdx.x >= N_ / 64) {
        const int base = (((blockIdx.x - N_ / 64) * 16 + blockIdx.y * 4 + blockIdx.z) * 256
                          + threadIdx.x) * 4;
        #pragma unroll
        for (int e0 = 0; e0 < 4; ++e0) {
            const int e = base + e0;
            if (e < 8192)        W16[e] = f2bf(theta_w[e] * LOG2E);
            else if (e < 16384)  W16[e] = f2bf(phi_w[e - 8192]);
            else if (e < 49152)  W16[e] = f2bf(g_w[e - 16384]);
            else                 ow16[e - 49152] = f2bf(o_w[e - 49152]);
        }
        return;
    }

    const int b = blockIdx.z, c0 = blockIdx.y * 64, n0 = blockIdx.x * 64;
    const int t = threadIdx.x;
    __shared__ float tile[64][65];

    const int cr = t >> 4, nc = (t & 15) * 4;
    #pragma unroll
    for (int it = 0; it < 4; ++it) {
        const float4 v = *(const float4*)(x + (size_t)(b * C_ + c0 + cr + it * 16) * N_ + n0 + nc);
        tile[cr + it * 16][nc + 0] = v.x; tile[cr + it * 16][nc + 1] = v.y;
        tile[cr + it * 16][nc + 2] = v.z; tile[cr + it * 16][nc + 3] = v.w;
    }
    __syncthreads();
    const int n = t >> 2, cg = (t & 3) * 16;
    union { u16 us[16]; uint4 u4[2]; } pk;
    #pragma unroll
    for (int e = 0; e < 16; ++e) pk.us[e] = f2bf(tile[cg + e][n]);
    uint4* dst = (uint4*)(xT16 + (size_t)(b * N_ + n0 + n) * C_ + c0 + cg);
    dst[0] = pk.u4[0]; dst[1] = pk.u4[1];
}

// ---------------------------------------------------------------------------
// Kernel 1: projections via MFMA. theta_t/phi_t [n][32] row-major. g stored
// UNSCALED in the PV B-fragment-tiled layout:
//   g2[((b*8 + ctile)*128 + jchunk)*512 + lane*8 + slot]
//   element (c, j): ctile=c>>4, lane=(c&15)+16*((j>>3)&3), slot=j&7,
//   jchunk=j>>5. A wave's PV B-frag load is then one contiguous 1 KB block.
// ---------------------------------------------------------------------------
__global__ __launch_bounds__(256) void proj_mfma_kernel(
    const u16* __restrict__ xT16, const u16* __restrict__ W16,
    const float* __restrict__ theta_b, const float* __restrict__ phi_b,
    const float* __restrict__ g_b,
    u16* __restrict__ theta_t, u16* __restrict__ phi_t, u16* __restrict__ g2)
{
    const int b = blockIdx.y, n0 = blockIdx.x * 64;
    const int w = threadIdx.x >> 6, lane = threadIdx.x & 63;
    const int lr = lane & 15, q = lane >> 4;
    const f32x4 zf = {0.f, 0.f, 0.f, 0.f};

    // ---- theta/phi: wave w owns pixel m-tile w ----
    const u16* xrow = xT16 + (size_t)(b * N_ + n0 + w * 16 + lr) * C_;
    f32x4 acc[4];
    #pragma unroll
    for (int nt = 0; nt < 4; ++nt) acc[nt] = zf;
    for (int ks = 0; ks < 8; ++ks) {
        const short8 aX = *(const short8*)(xrow + ks * 32 + q * 8);
        #pragma unroll
        for (int nt = 0; nt < 4; ++nt) {
            const short8 bW = *(const short8*)(W16 + (size_t)(nt * 16 + lr) * C_ + ks * 32 + q * 8);
            acc[nt] = __builtin_amdgcn_mfma_f32_16x16x32_bf16(aX, bW, acc[nt], 0, 0, 0);
        }
    }
    #pragma unroll
    for (int nt = 0; nt < 4; ++nt) {
        const int o = nt * 16 + lr;
        #pragma unroll
        for (int reg = 0; reg < 4; ++reg) {
            const int n = n0 + w * 16 + q * 4 + reg;
            if (nt < 2)
                theta_t[(size_t)(b * N_ + n) * CK_ + o] = f2bf(acc[nt][reg] + theta_b[o] * LOG2E);
            else
                phi_t[(size_t)(b * N_ + n) * CK_ + (o - 32)] = f2bf(acc[nt][reg] + phi_b[o - 32]);
        }
    }

    // ---- g: wave w owns c m-tiles {2w, 2w+1}; store in frag-tiled layout ----
    #pragma unroll
    for (int mp = 0; mp < 2; ++mp) {
        const int ctile = w * 2 + mp;
        const int crow = ctile * 16;
        f32x4 ag[4];
        #pragma unroll
        for (int nt = 0; nt < 4; ++nt) ag[nt] = zf;
        for (int ks = 0; ks < 8; ++ks) {
            const short8 aW = *(const short8*)(W16 + (size_t)(64 + crow + lr) * C_ + ks * 32 + q * 8);
            #pragma unroll
            for (int nt = 0; nt < 4; ++nt) {
                const short8 bX = *(const short8*)(xT16 + (size_t)(b * N_ + n0 + nt * 16 + lr) * C_ + ks * 32 + q * 8);
                ag[nt] = __builtin_amdgcn_mfma_f32_16x16x32_bf16(aW, bX, ag[nt], 0, 0, 0);
            }
        }
        #pragma unroll
        for (int nt = 0; nt < 4; ++nt) {
            const int jchunk = (n0 >> 5) + (nt >> 1);
            const int lhi = (nt & 1) * 2 + (lr >> 3);
            #pragma unroll
            for (int reg = 0; reg < 4; ++reg) {
                const int c = crow + q * 4 + reg;
                const int lane2 = (q * 4 + reg) + 16 * lhi;
                g2[((size_t)(b * 8 + ctile) * 128 + jchunk) * 512 + lane2 * 8 + (lr & 7)]
                    = f2bf(ag[nt][reg] + g_b[c]);
            }
        }
    }
}

// ---------------------------------------------------------------------------
// Kernel 2: Z[b][j] = sum_i exp2(S[i][j]) via MFMA (R1-proven). Grid (N/32,4,B).
// ---------------------------------------------------------------------------
__global__ __launch_bounds__(256) void colstats_kernel(
    const u16* __restrict__ theta_t, const u16* __restrict__ phi_t,
    float* __restrict__ Z)
{
    const int b  = blockIdx.z;
    const int j0 = blockIdx.x * 32;
    const int istart = blockIdx.y * (N_ / 4);
    const int tid = threadIdx.x;
    const int wave = tid >> 6, lane = tid & 63;
    const int lr = lane & 15, q = lane >> 4;

    const int jW = j0 + (wave & 1) * 16;
    const short8 bF = *(const short8*)(phi_t + (size_t)(b * N_ + jW + lr) * CK_ + q * 8);

    const u16* thp = theta_t + (size_t)b * N_ * CK_;
    const f32x4 zero = {0.f, 0.f, 0.f, 0.f};
    float zacc = 0.f;
    for (int it = istart + (wave >> 1) * 16; it < istart + N_ / 4; it += 32) {
        const short8 aF = *(const short8*)(thp + (size_t)(it + lr) * CK_ + q * 8);
        f32x4 S = __builtin_amdgcn_mfma_f32_16x16x32_bf16(aF, bF, zero, 0, 0, 0);
        zacc += fexp2(S[0]) + fexp2(S[1]) + fexp2(S[2]) + fexp2(S[3]);
    }
    zacc += __shfl_xor(zacc, 16);
    zacc += __shfl_xor(zacc, 32);
    if (lane < 16) atomicAdd(&Z[(size_t)b * N_ + jW + lr], zacc);
}

// ---------------------------------------------------------------------------
// Kernel 3: fold 1/Z into g2 (in place, bf16). R5-proven.
// j = jchunk*32 + ((lane2>>4)<<3) + slot. idx>>19 = b; (idx>>9)&127 = jchunk;
// (idx>>7)&3 = lane2>>4.
// ---------------------------------------------------------------------------
__global__ __launch_bounds__(256) void gscale_kernel(
    u16* __restrict__ g2, const float* __restrict__ Z)
{
    const size_t idx = ((size_t)blockIdx.x * 256 + threadIdx.x) * 8;
    const int b = (int)(idx >> 19);
    const int j = (int)(((idx >> 9) & 127) * 32 + ((idx >> 7) & 3) * 8);
    uint4 raw = *(const uint4*)(g2 + idx);
    const float4 z0 = *(const float4*)(Z + (size_t)b * N_ + j);
    const float4 z1 = *(const float4*)(Z + (size_t)b * N_ + j + 4);
    const float zz[8] = {z0.x, z0.y, z0.z, z0.w, z1.x, z1.y, z1.z, z1.w};
    u16* pr = (u16*)&raw;
    union { u16 us[8]; uint4 u4; } pk;
    #pragma unroll
    for (int k = 0; k < 8; ++k) pk.us[k] = f2bf(bf2f(pr[k]) * frcp(zz[k]));
    *(uint4*)(g2 + idx) = pk.u4;
}

// ---------------------------------------------------------------------------
// Kernel 4: o_pre partial. Barrier-free, LDS-free (R5-proven core).
// SINGLE DELTA vs R5: c split 8-way (ct=1 c-tile/wave, was 2) -> grid 1024
// blocks = 4096 waves = 4 waves/SIMD (R5: 2/SIMD, 18% occupancy,
// latency-bound). fp32 o_p0/o_p1 partial path byte-identical to R5.
// Store lane2 high bits: ct*2+(lr>>3) -> (ch&1)*2+(lr>>3) (even/odd ch waves
// fill disjoint halves of the same ks granule; bijective, no race).
// ---------------------------------------------------------------------------
__global__ __launch_bounds__(256, 4) void opre_kernel(
    const u16* __restrict__ theta_t, const u16* __restrict__ phi_t,
    const u16* __restrict__ g2,
    float* __restrict__ o_p0, float* __restrict__ o_p1)
{
    const int bx = blockIdx.x;
    const int igg = bx & 15, ch = (bx >> 4) & 7, jh = (bx >> 7) & 1, b = bx >> 8;
    const int w = threadIdx.x >> 6, lane = threadIdx.x & 63;
    const int lr = lane & 15, q = lane >> 4;
    const int i0 = (igg * 4 + w) * 64;
    const f32x4 zf = {0.f, 0.f, 0.f, 0.f};

    // theta B-frags for 4 i-tiles
    short8 bT[4];
    #pragma unroll
    for (int it = 0; it < 4; ++it)
        bT[it] = *(const short8*)(theta_t + (size_t)(b * N_ + i0 + it * 16 + lr) * CK_ + q * 8);

    // phi A-frag row permutation (row r <-> j = (r>>2)*8 + (r&3))
    const int ja = (lr >> 2) * 8 + (lr & 3);
    const int jstart = jh * (N_ / 2);
    const u16* pA = phi_t + ((size_t)(b * N_) + jstart + ja) * CK_ + q * 8;
    const u16* pG = g2 + ((size_t)(b * 8 + ch) * 128 + jh * 64) * 512 + lane * 8;

    f32x4 acc[4];
    #pragma unroll
    for (int it = 0; it < 4; ++it) acc[it] = zf;

    // depth-2 prefetch (named registers, ping-pong)
    short8 A0a = *(const short8*)(pA);
    short8 A1a = *(const short8*)(pA + 4 * CK_);
    short8 G0a = *(const short8*)(pG);
    short8 A0b = *(const short8*)(pA + 32 * CK_);
    short8 A1b = *(const short8*)(pA + 36 * CK_);
    short8 G0b = *(const short8*)(pG + 512);

#define OPRE_CHUNK(K, A0r, A1r, G0r)                                               \
    {                                                                               \
        const short8 cA0 = A0r, cA1 = A1r, cG0 = G0r;                               \
        f32x4 Sa[4], Sb[4];                                                         \
        _Pragma("unroll")                                                           \
        for (int it = 0; it < 4; ++it) {                                            \
            Sa[it] = __builtin_amdgcn_mfma_f32_16x16x32_bf16(cA0, bT[it], zf, 0, 0, 0); \
            Sb[it] = __builtin_amdgcn_mfma_f32_16x16x32_bf16(cA1, bT[it], zf, 0, 0, 0); \
        }                                                                           \
        const int kn = ((K) + 2) & 63;                                              \
        A0r = *(const short8*)(pA + (size_t)kn * (32 * CK_));                       \
        A1r = *(const short8*)(pA + (size_t)kn * (32 * CK_) + 4 * CK_);             \
        G0r = *(const short8*)(pG + kn * 512);                                      \
        _Pragma("unroll")                                                           \
        for (int it = 0; it < 4; ++it) {                                            \
            union { u32 u[4]; short8 s8; } ef;                                      \
            ef.u[0] = cvt_pk_bf16(fexp2(Sa[it][0]), fexp2(Sa[it][1]));              \
            ef.u[1] = cvt_pk_bf16(fexp2(Sa[it][2]), fexp2(Sa[it][3]));              \
            ef.u[2] = cvt_pk_bf16(fexp2(Sb[it][0]), fexp2(Sb[it][1]));              \
            ef.u[3] = cvt_pk_bf16(fexp2(Sb[it][2]), fexp2(Sb[it][3]));              \
            acc[it] = __builtin_amdgcn_mfma_f32_16x16x32_bf16(ef.s8, cG0, acc[it], 0, 0, 0); \
        }                                                                           \
    }

    for (int k = 0; k < 64; k += 2) {
        OPRE_CHUNK(k,     A0a, A1a, G0a)
        OPRE_CHUNK(k + 1, A0b, A1b, G0b)
    }
#undef OPRE_CHUNK

    // store fp32 partials in final's B-frag-tiled layout:
    // op[(((b*256 + ntile)*4 + ks)*64 + lane')*8 + slot], ks = ch>>1
    float* op = (jh ? o_p1 : o_p0);
    #pragma unroll
    for (int it = 0; it < 4; ++it) {
        const size_t tb = ((size_t)(b * 256 + (i0 >> 4) + it) * 4 + (ch >> 1)) * 512;
        #pragma unroll
        for (int reg = 0; reg < 4; ++reg) {
            const int lane2 = (q * 4 + reg) + 16 * ((ch & 1) * 2 + (lr >> 3));
            op[tb + lane2 * 8 + (lr & 7)] = acc[it][reg];
        }
    }
}

// ---------------------------------------------------------------------------
// Kernel 5: out = x + gamma * (o_w @ (o_p0 + o_p1) + o_b) via MFMA.
// o_p frag-tiled -> bP loads are contiguous float4s. (R5-proven, unchanged.)
// Grid (N/32, B) = 512 blocks, block 256 (4 waves).
// ---------------------------------------------------------------------------
__global__ __launch_bounds__(256) void final_mfma_kernel(
    const float* __restrict__ o_p0, const float* __restrict__ o_p1,
    const u16* __restrict__ ow16, const float* __restrict__ o_b,
    const float* __restrict__ gamma, const float* __restrict__ x,
    float* __restrict__ out)
{
    const int b = blockIdx.y, n0 = blockIdx.x * 32;
    const int w = threadIdx.x >> 6, lane = threadIdx.x & 63;
    const int lr = lane & 15, q = lane >> 4;
    const f32x4 zf = {0.f, 0.f, 0.f, 0.f};

    f32x4 acc[4][2];
    #pragma unroll
    for (int mt = 0; mt < 4; ++mt)
        #pragma unroll
        for (int nt = 0; nt < 2; ++nt) acc[mt][nt] = zf;

    for (int ks = 0; ks < 4; ++ks) {
        short8 bP[2];
        #pragma unroll
        for (int nt = 0; nt < 2; ++nt) {
            const size_t base = (((size_t)(b * 256 + (n0 >> 4) + nt) * 4 + ks) * 64 + lane) * 8;
            const float4 a0 = *(const float4*)(o_p0 + base);
            const float4 a1 = *(const float4*)(o_p0 + base + 4);
            const float4 c0 = *(const float4*)(o_p1 + base);
            const float4 c1 = *(const float4*)(o_p1 + base + 4);
            union { u32 u[4]; short8 s8; } pk;
            pk.u[0] = cvt_pk_bf16(a0.x + c0.x, a0.y + c0.y);
            pk.u[1] = cvt_pk_bf16(a0.z + c0.z, a0.w + c0.w);
            pk.u[2] = cvt_pk_bf16(a1.x + c1.x, a1.y + c1.y);
            pk.u[3] = cvt_pk_bf16(a1.z + c1.z, a1.w + c1.w);
            bP[nt] = pk.s8;
        }
        #pragma unroll
        for (int mt = 0; mt < 4; ++mt) {
            const short8 aW = *(const short8*)(ow16 + (size_t)((w * 4 + mt) * 16 + lr) * CV_ + ks * 32 + q * 8);
            #pragma unroll
            for (int nt = 0; nt < 2; ++nt)
                acc[mt][nt] = __builtin_amdgcn_mfma_f32_16x16x32_bf16(aW, bP[nt], acc[mt][nt], 0, 0, 0);
        }
    }

    const float gm = gamma[0];
    #pragma unroll
    for (int mt = 0; mt < 4; ++mt) {
        #pragma unroll
        for (int nt = 0; nt < 2; ++nt) {
            #pragma unroll
            for (int reg = 0; reg < 4; ++reg) {
                const int oc = (w * 4 + mt) * 16 + q * 4 + reg;
                const int n = n0 + nt * 16 + lr;
                const size_t off = (size_t)(b * C_ + oc) * N_ + n;
                out[off] = x[off] + gm * (acc[mt][nt][reg] + o_b[oc]);
            }
        }
    }
}

// ---------------------------------------------------------------------------
extern "C" void kernel_launch(void* const* d_in, const int* in_sizes, int n_in,
                              void* d_out, int out_size, void* d_ws, size_t ws_size,
                              hipStream_t stream)
{
    const float* x       = (const float*)d_in[0];
    const float* theta_w = (const float*)d_in[1];
    const float* theta_b = (const float*)d_in[2];
    const float* phi_w   = (const float*)d_in[3];
    const float* phi_b   = (const float*)d_in[4];
    const float* g_w     = (const float*)d_in[5];
    const float* g_b     = (const float*)d_in[6];
    const float* o_w     = (const float*)d_in[7];
    const float* o_b     = (const float*)d_in[8];
    const float* gamma   = (const float*)d_in[9];
    float* out = (float*)d_out;

    // workspace: xT16 8MB | W16 96KB | ow16 64KB | theta_t 1MB | phi_t 1MB |
    //            g2 4MB | Z 64KB | o_p0 8MB | o_p1 8MB   (~31 MB)
    u16* xT16    = (u16*)d_ws;
    u16* W16     = xT16 + (size_t)B_ * N_ * C_;
    u16* ow16    = W16 + 192 * C_;
    u16* theta_t = ow16 + C_ * CV_;
    u16* phi_t   = theta_t + (size_t)B_ * N_ * CK_;
    u16* g2      = phi_t + (size_t)B_ * N_ * CK_;
    float* Z     = (float*)(g2 + (size_t)B_ * CV_ * N_);
    float* o_p0  = Z + (size_t)B_ * N_;
    float* o_p1  = o_p0 + (size_t)B_ * N_ * CV_;

    hipMemsetAsync(Z, 0, (size_t)B_ * N_ * sizeof(float), stream);

    prep_kernel<<<dim3(N_ / 64 + 5, C_ / 64, B_), 256, 0, stream>>>(
        x, xT16, theta_w, phi_w, g_w, o_w, W16, ow16);
    proj_mfma_kernel<<<dim3(N_ / 64, B_), 256, 0, stream>>>(
        xT16, W16, theta_b, phi_b, g_b, theta_t, phi_t, g2);
    colstats_kernel<<<dim3(N_ / 32, 4, B_), 256, 0, stream>>>(theta_t, phi_t, Z);
    gscale_kernel<<<dim3((B_ * CV_ * N_) / 2048), 256, 0, stream>>>(g2, Z);
    opre_kernel<<<dim3(1024), 256, 0, stream>>>(theta_t, phi_t, g2, o_p0, o_p1);
    final_mfma_kernel<<<dim3(N_ / 32, B_), 256, 0, stream>>>(
        o_p0, o_p1, ow16, o_b, gamma, x, out);
}

// Round 8
// 200.428 us; speedup vs baseline: 1.0460x; 1.0460x over previous
//
#include <hip/hip_runtime.h>
#include <math.h>

// Problem constants
#define B_  4
#define C_  256
#define N_  4096
#define CK_ 32
#define CV_ 128

typedef __attribute__((ext_vector_type(8))) short short8;  // 8 bf16 = 4 VGPRs
typedef __attribute__((ext_vector_type(4))) float f32x4;   // MFMA C/D frag
typedef unsigned short u16;
typedef unsigned int   u32;

static constexpr float LOG2E = 1.4426950408889634f;

static __device__ __forceinline__ u16 f2bf(float f) {       // fp32 -> bf16 RNE
    u32 u = __float_as_uint(f);
    u = (u + 0x7FFFu + ((u >> 16) & 1u)) >> 16;
    return (u16)u;
}
static __device__ __forceinline__ float bf2f(u16 h) {
    return __uint_as_float(((u32)h) << 16);
}

// native transcendentals
static __device__ __forceinline__ float fexp2(float x) {
#if __has_builtin(__builtin_amdgcn_exp2f)
    return __builtin_amdgcn_exp2f(x);
#else
    float r; asm("v_exp_f32 %0, %1\n\ts_nop 0" : "=v"(r) : "v"(x)); return r;
#endif
}
static __device__ __forceinline__ float frcp(float x) {
#if __has_builtin(__builtin_amdgcn_rcpf)
    return __builtin_amdgcn_rcpf(x);
#else
    float r; asm("v_rcp_f32 %0, %1\n\ts_nop 0" : "=v"(r) : "v"(x)); return r;
#endif
}
// pack two fp32 -> 2x bf16 (RNE), lo = a, hi = b
static __device__ __forceinline__ u32 cvt_pk_bf16(float a, float b) {
    u32 r; asm("v_cvt_pk_bf16_f32 %0, %1, %2" : "=v"(r) : "v"(a), "v"(b));
    return r;
}

// ---------------------------------------------------------------------------
// Kernel 0: prep = x transpose/convert  +  weight convert (merged).
// ---------------------------------------------------------------------------
__global__ __launch_bounds__(256) void prep_kernel(
    const float* __restrict__ x, u16* __restrict__ xT16,
    const float* __restrict__ theta_w, const float* __restrict__ phi_w,
    const float* __restrict__ g_w,     const float* __restrict__ o_w,
    u16* __restrict__ W16, u16* __restrict__ ow16)
{
    if (blockIdx.x >= N_ / 64) {
        const int base = (((blockIdx.x - N_ / 64) * 16 + blockIdx.y * 4 + blockIdx.z) * 256
                          + threadIdx.x) * 4;
        #pragma unroll
        for (int e0 = 0; e0 < 4; ++e0) {
            const int e = base + e0;
            if (e < 8192)        W16[e] = f2bf(theta_w[e] * LOG2E);
            else if (e < 16384)  W16[e] = f2bf(phi_w[e - 8192]);
            else if (e < 49152)  W16[e] = f2bf(g_w[e - 16384]);
            else                 ow16[e - 49152] = f2bf(o_w[e - 49152]);
        }
        return;
    }

    const int b = blockIdx.z, c0 = blockIdx.y * 64, n0 = blockIdx.x * 64;
    const int t = threadIdx.x;
    __shared__ float tile[64][65];

    const int cr = t >> 4, nc = (t & 15) * 4;
    #pragma unroll
    for (int it = 0; it < 4; ++it) {
        const float4 v = *(const float4*)(x + (size_t)(b * C_ + c0 + cr + it * 16) * N_ + n0 + nc);
        tile[cr + it * 16][nc + 0] = v.x; tile[cr + it * 16][nc + 1] = v.y;
        tile[cr + it * 16][nc + 2] = v.z; tile[cr + it * 16][nc + 3] = v.w;
    }
    __syncthreads();
    const int n = t >> 2, cg = (t & 3) * 16;
    union { u16 us[16]; uint4 u4[2]; } pk;
    #pragma unroll
    for (int e = 0; e < 16; ++e) pk.us[e] = f2bf(tile[cg + e][n]);
    uint4* dst = (uint4*)(xT16 + (size_t)(b * N_ + n0 + n) * C_ + c0 + cg);
    dst[0] = pk.u4[0]; dst[1] = pk.u4[1];
}

// ---------------------------------------------------------------------------
// Kernel 1: projections via MFMA. theta_t/phi_t [n][32] row-major. g stored
// UNSCALED in the PV B-fragment-tiled layout:
//   g2[((b*8 + ctile)*128 + jchunk)*512 + lane*8 + slot]
//   element (c, j): ctile=c>>4, lane=(c&15)+16*((j>>3)&3), slot=j&7,
//   jchunk=j>>5. A wave's PV B-frag load is then one contiguous 1 KB block.
// ---------------------------------------------------------------------------
__global__ __launch_bounds__(256) void proj_mfma_kernel(
    const u16* __restrict__ xT16, const u16* __restrict__ W16,
    const float* __restrict__ theta_b, const float* __restrict__ phi_b,
    const float* __restrict__ g_b,
    u16* __restrict__ theta_t, u16* __restrict__ phi_t, u16* __restrict__ g2)
{
    const int b = blockIdx.y, n0 = blockIdx.x * 64;
    const int w = threadIdx.x >> 6, lane = threadIdx.x & 63;
    const int lr = lane & 15, q = lane >> 4;
    const f32x4 zf = {0.f, 0.f, 0.f, 0.f};

    // ---- theta/phi: wave w owns pixel m-tile w ----
    const u16* xrow = xT16 + (size_t)(b * N_ + n0 + w * 16 + lr) * C_;
    f32x4 acc[4];
    #pragma unroll
    for (int nt = 0; nt < 4; ++nt) acc[nt] = zf;
    for (int ks = 0; ks < 8; ++ks) {
        const short8 aX = *(const short8*)(xrow + ks * 32 + q * 8);
        #pragma unroll
        for (int nt = 0; nt < 4; ++nt) {
            const short8 bW = *(const short8*)(W16 + (size_t)(nt * 16 + lr) * C_ + ks * 32 + q * 8);
            acc[nt] = __builtin_amdgcn_mfma_f32_16x16x32_bf16(aX, bW, acc[nt], 0, 0, 0);
        }
    }
    #pragma unroll
    for (int nt = 0; nt < 4; ++nt) {
        const int o = nt * 16 + lr;
        #pragma unroll
        for (int reg = 0; reg < 4; ++reg) {
            const int n = n0 + w * 16 + q * 4 + reg;
            if (nt < 2)
                theta_t[(size_t)(b * N_ + n) * CK_ + o] = f2bf(acc[nt][reg] + theta_b[o] * LOG2E);
            else
                phi_t[(size_t)(b * N_ + n) * CK_ + (o - 32)] = f2bf(acc[nt][reg] + phi_b[o - 32]);
        }
    }

    // ---- g: wave w owns c m-tiles {2w, 2w+1}; store in frag-tiled layout ----
    #pragma unroll
    for (int mp = 0; mp < 2; ++mp) {
        const int ctile = w * 2 + mp;
        const int crow = ctile * 16;
        f32x4 ag[4];
        #pragma unroll
        for (int nt = 0; nt < 4; ++nt) ag[nt] = zf;
        for (int ks = 0; ks < 8; ++ks) {
            const short8 aW = *(const short8*)(W16 + (size_t)(64 + crow + lr) * C_ + ks * 32 + q * 8);
            #pragma unroll
            for (int nt = 0; nt < 4; ++nt) {
                const short8 bX = *(const short8*)(xT16 + (size_t)(b * N_ + n0 + nt * 16 + lr) * C_ + ks * 32 + q * 8);
                ag[nt] = __builtin_amdgcn_mfma_f32_16x16x32_bf16(aW, bX, ag[nt], 0, 0, 0);
            }
        }
        #pragma unroll
        for (int nt = 0; nt < 4; ++nt) {
            const int jchunk = (n0 >> 5) + (nt >> 1);
            const int lhi = (nt & 1) * 2 + (lr >> 3);
            #pragma unroll
            for (int reg = 0; reg < 4; ++reg) {
                const int c = crow + q * 4 + reg;
                const int lane2 = (q * 4 + reg) + 16 * lhi;
                g2[((size_t)(b * 8 + ctile) * 128 + jchunk) * 512 + lane2 * 8 + (lr & 7)]
                    = f2bf(ag[nt][reg] + g_b[c]);
            }
        }
    }
}

// ---------------------------------------------------------------------------
// Kernel 2: Z[b][j] = sum_i exp2(S[i][j]) via MFMA (R1-proven). Grid (N/32,4,B).
// ---------------------------------------------------------------------------
__global__ __launch_bounds__(256) void colstats_kernel(
    const u16* __restrict__ theta_t, const u16* __restrict__ phi_t,
    float* __restrict__ Z)
{
    const int b  = blockIdx.z;
    const int j0 = blockIdx.x * 32;
    const int istart = blockIdx.y * (N_ / 4);
    const int tid = threadIdx.x;
    const int wave = tid >> 6, lane = tid & 63;
    const int lr = lane & 15, q = lane >> 4;

    const int jW = j0 + (wave & 1) * 16;
    const short8 bF = *(const short8*)(phi_t + (size_t)(b * N_ + jW + lr) * CK_ + q * 8);

    const u16* thp = theta_t + (size_t)b * N_ * CK_;
    const f32x4 zero = {0.f, 0.f, 0.f, 0.f};
    float zacc = 0.f;
    for (int it = istart + (wave >> 1) * 16; it < istart + N_ / 4; it += 32) {
        const short8 aF = *(const short8*)(thp + (size_t)(it + lr) * CK_ + q * 8);
        f32x4 S = __builtin_amdgcn_mfma_f32_16x16x32_bf16(aF, bF, zero, 0, 0, 0);
        zacc += fexp2(S[0]) + fexp2(S[1]) + fexp2(S[2]) + fexp2(S[3]);
    }
    zacc += __shfl_xor(zacc, 16);
    zacc += __shfl_xor(zacc, 32);
    if (lane < 16) atomicAdd(&Z[(size_t)b * N_ + jW + lr], zacc);
}

// ---------------------------------------------------------------------------
// Kernel 3: fold 1/Z into g2 (in place, bf16). R5-proven.
// ---------------------------------------------------------------------------
__global__ __launch_bounds__(256) void gscale_kernel(
    u16* __restrict__ g2, const float* __restrict__ Z)
{
    const size_t idx = ((size_t)blockIdx.x * 256 + threadIdx.x) * 8;
    const int b = (int)(idx >> 19);
    const int j = (int)(((idx >> 9) & 127) * 32 + ((idx >> 7) & 3) * 8);
    uint4 raw = *(const uint4*)(g2 + idx);
    const float4 z0 = *(const float4*)(Z + (size_t)b * N_ + j);
    const float4 z1 = *(const float4*)(Z + (size_t)b * N_ + j + 4);
    const float zz[8] = {z0.x, z0.y, z0.z, z0.w, z1.x, z1.y, z1.z, z1.w};
    u16* pr = (u16*)&raw;
    union { u16 us[8]; uint4 u4; } pk;
    #pragma unroll
    for (int k = 0; k < 8; ++k) pk.us[k] = f2bf(bf2f(pr[k]) * frcp(zz[k]));
    *(uint4*)(g2 + idx) = pk.u4;
}

// ---------------------------------------------------------------------------
// Kernel 4: o_pre partial. Barrier-free, LDS-free (R5-proven dataflow).
// SINGLE DELTA vs R5/R7: IT=8 i-tiles per wave (128 i), CT=2 c-tiles (as R5).
// Line-model: total request bytes = 1.05GB*(2+CT)/(IT*CT) = 262MB (R5: 524,
// R7: 786) -> TCP-bound time ~25us at measured ~3.7cy/64B-line/CU.
// Grid 256 blocks = 1024 waves = 1 wave/SIMD (line-bound, occupancy moot).
// Store formulas byte-identical to R5 (ks=ch, lane2 = (q*4+reg)+16*(ct*2+
// (lr>>3))), fp32 o_p0/o_p1 partial path unchanged.
// ---------------------------------------------------------------------------
__global__ __launch_bounds__(256, 1) void opre_kernel(
    const u16* __restrict__ theta_t, const u16* __restrict__ phi_t,
    const u16* __restrict__ g2,
    float* __restrict__ o_p0, float* __restrict__ o_p1)
{
    const int bx = blockIdx.x;
    const int igg = bx & 7, ch = (bx >> 3) & 3, jh = (bx >> 5) & 1, b = bx >> 6;
    const int w = threadIdx.x >> 6, lane = threadIdx.x & 63;
    const int lr = lane & 15, q = lane >> 4;
    const int i0 = (igg * 4 + w) * 128;       // 8 i-tiles per wave
    const f32x4 zf = {0.f, 0.f, 0.f, 0.f};

    // theta B-frags for 8 i-tiles
    short8 bT[8];
    #pragma unroll
    for (int it = 0; it < 8; ++it)
        bT[it] = *(const short8*)(theta_t + (size_t)(b * N_ + i0 + it * 16 + lr) * CK_ + q * 8);

    // phi A-frag row permutation (row r <-> j = (r>>2)*8 + (r&3))
    const int ja = (lr >> 2) * 8 + (lr & 3);
    const int jstart = jh * (N_ / 2);
    const u16* pA = phi_t + ((size_t)(b * N_) + jstart + ja) * CK_ + q * 8;
    const u16* pG = g2 + ((size_t)(b * 8 + ch * 2) * 128 + jh * 64) * 512 + lane * 8;

    f32x4 acc[8][2];
    #pragma unroll
    for (int it = 0; it < 8; ++it) { acc[it][0] = zf; acc[it][1] = zf; }

    // depth-2 prefetch (named registers, ping-pong)
    short8 A0a = *(const short8*)(pA);
    short8 A1a = *(const short8*)(pA + 4 * CK_);
    short8 G0a = *(const short8*)(pG);
    short8 G1a = *(const short8*)(pG + 128 * 512);
    short8 A0b = *(const short8*)(pA + 32 * CK_);
    short8 A1b = *(const short8*)(pA + 36 * CK_);
    short8 G0b = *(const short8*)(pG + 512);
    short8 G1b = *(const short8*)(pG + 128 * 512 + 512);

#define OPRE_CHUNK(K, A0r, A1r, G0r, G1r)                                          \
    {                                                                               \
        const short8 cA0 = A0r, cA1 = A1r, cG0 = G0r, cG1 = G1r;                    \
        const int kn = ((K) + 2) & 63;                                              \
        A0r = *(const short8*)(pA + (size_t)kn * (32 * CK_));                       \
        A1r = *(const short8*)(pA + (size_t)kn * (32 * CK_) + 4 * CK_);             \
        G0r = *(const short8*)(pG + kn * 512);                                      \
        G1r = *(const short8*)(pG + 128 * 512 + kn * 512);                          \
        _Pragma("unroll")                                                           \
        for (int it = 0; it < 8; ++it) {                                            \
            const f32x4 Sa = __builtin_amdgcn_mfma_f32_16x16x32_bf16(cA0, bT[it], zf, 0, 0, 0); \
            const f32x4 Sb = __builtin_amdgcn_mfma_f32_16x16x32_bf16(cA1, bT[it], zf, 0, 0, 0); \
            union { u32 u[4]; short8 s8; } ef;                                      \
            ef.u[0] = cvt_pk_bf16(fexp2(Sa[0]), fexp2(Sa[1]));                      \
            ef.u[1] = cvt_pk_bf16(fexp2(Sa[2]), fexp2(Sa[3]));                      \
            ef.u[2] = cvt_pk_bf16(fexp2(Sb[0]), fexp2(Sb[1]));                      \
            ef.u[3] = cvt_pk_bf16(fexp2(Sb[2]), fexp2(Sb[3]));                      \
            acc[it][0] = __builtin_amdgcn_mfma_f32_16x16x32_bf16(ef.s8, cG0, acc[it][0], 0, 0, 0); \
            acc[it][1] = __builtin_amdgcn_mfma_f32_16x16x32_bf16(ef.s8, cG1, acc[it][1], 0, 0, 0); \
        }                                                                           \
    }

    for (int k = 0; k < 64; k += 2) {
        OPRE_CHUNK(k,     A0a, A1a, G0a, G1a)
        OPRE_CHUNK(k + 1, A0b, A1b, G0b, G1b)
    }
#undef OPRE_CHUNK

    // store fp32 partials in final's B-frag-tiled layout (R5 formulas):
    // op[(((b*256 + ntile)*4 + ks)*64 + lane')*8 + slot], ks = ch
    float* op = (jh ? o_p1 : o_p0);
    #pragma unroll
    for (int it = 0; it < 8; ++it) {
        const size_t tb = ((size_t)(b * 256 + (i0 >> 4) + it) * 4 + ch) * 512;
        #pragma unroll
        for (int ct = 0; ct < 2; ++ct) {
            #pragma unroll
            for (int reg = 0; reg < 4; ++reg) {
                const int lane2 = (q * 4 + reg) + 16 * (ct * 2 + (lr >> 3));
                op[tb + lane2 * 8 + (lr & 7)] = acc[it][ct][reg];
            }
        }
    }
}

// ---------------------------------------------------------------------------
// Kernel 5: out = x + gamma * (o_w @ (o_p0 + o_p1) + o_b) via MFMA.
// (R5-proven, unchanged.) Grid (N/32, B) = 512 blocks, block 256 (4 waves).
// ---------------------------------------------------------------------------
__global__ __launch_bounds__(256) void final_mfma_kernel(
    const float* __restrict__ o_p0, const float* __restrict__ o_p1,
    const u16* __restrict__ ow16, const float* __restrict__ o_b,
    const float* __restrict__ gamma, const float* __restrict__ x,
    float* __restrict__ out)
{
    const int b = blockIdx.y, n0 = blockIdx.x * 32;
    const int w = threadIdx.x >> 6, lane = threadIdx.x & 63;
    const int lr = lane & 15, q = lane >> 4;
    const f32x4 zf = {0.f, 0.f, 0.f, 0.f};

    f32x4 acc[4][2];
    #pragma unroll
    for (int mt = 0; mt < 4; ++mt)
        #pragma unroll
        for (int nt = 0; nt < 2; ++nt) acc[mt][nt] = zf;

    for (int ks = 0; ks < 4; ++ks) {
        short8 bP[2];
        #pragma unroll
        for (int nt = 0; nt < 2; ++nt) {
            const size_t base = (((size_t)(b * 256 + (n0 >> 4) + nt) * 4 + ks) * 64 + lane) * 8;
            const float4 a0 = *(const float4*)(o_p0 + base);
            const float4 a1 = *(const float4*)(o_p0 + base + 4);
            const float4 c0 = *(const float4*)(o_p1 + base);
            const float4 c1 = *(const float4*)(o_p1 + base + 4);
            union { u32 u[4]; short8 s8; } pk;
            pk.u[0] = cvt_pk_bf16(a0.x + c0.x, a0.y + c0.y);
            pk.u[1] = cvt_pk_bf16(a0.z + c0.z, a0.w + c0.w);
            pk.u[2] = cvt_pk_bf16(a1.x + c1.x, a1.y + c1.y);
            pk.u[3] = cvt_pk_bf16(a1.z + c1.z, a1.w + c1.w);
            bP[nt] = pk.s8;
        }
        #pragma unroll
        for (int mt = 0; mt < 4; ++mt) {
            const short8 aW = *(const short8*)(ow16 + (size_t)((w * 4 + mt) * 16 + lr) * CV_ + ks * 32 + q * 8);
            #pragma unroll
            for (int nt = 0; nt < 2; ++nt)
                acc[mt][nt] = __builtin_amdgcn_mfma_f32_16x16x32_bf16(aW, bP[nt], acc[mt][nt], 0, 0, 0);
        }
    }

    const float gm = gamma[0];
    #pragma unroll
    for (int mt = 0; mt < 4; ++mt) {
        #pragma unroll
        for (int nt = 0; nt < 2; ++nt) {
            #pragma unroll
            for (int reg = 0; reg < 4; ++reg) {
                const int oc = (w * 4 + mt) * 16 + q * 4 + reg;
                const int n = n0 + nt * 16 + lr;
                const size_t off = (size_t)(b * C_ + oc) * N_ + n;
                out[off] = x[off] + gm * (acc[mt][nt][reg] + o_b[oc]);
            }
        }
    }
}

// ---------------------------------------------------------------------------
extern "C" void kernel_launch(void* const* d_in, const int* in_sizes, int n_in,
                              void* d_out, int out_size, void* d_ws, size_t ws_size,
                              hipStream_t stream)
{
    const float* x       = (const float*)d_in[0];
    const float* theta_w = (const float*)d_in[1];
    const float* theta_b = (const float*)d_in[2];
    const float* phi_w   = (const float*)d_in[3];
    const float* phi_b   = (const float*)d_in[4];
    const float* g_w     = (const float*)d_in[5];
    const float* g_b     = (const float*)d_in[6];
    const float* o_w     = (const float*)d_in[7];
    const float* o_b     = (const float*)d_in[8];
    const float* gamma   = (const float*)d_in[9];
    float* out = (float*)d_out;

    // workspace: xT16 8MB | W16 96KB | ow16 64KB | theta_t 1MB | phi_t 1MB |
    //            g2 4MB | Z 64KB | o_p0 8MB | o_p1 8MB   (~31 MB)
    u16* xT16    = (u16*)d_ws;
    u16* W16     = xT16 + (size_t)B_ * N_ * C_;
    u16* ow16    = W16 + 192 * C_;
    u16* theta_t = ow16 + C_ * CV_;
    u16* phi_t   = theta_t + (size_t)B_ * N_ * CK_;
    u16* g2      = phi_t + (size_t)B_ * N_ * CK_;
    float* Z     = (float*)(g2 + (size_t)B_ * CV_ * N_);
    float* o_p0  = Z + (size_t)B_ * N_;
    float* o_p1  = o_p0 + (size_t)B_ * N_ * CV_;

    hipMemsetAsync(Z, 0, (size_t)B_ * N_ * sizeof(float), stream);

    prep_kernel<<<dim3(N_ / 64 + 5, C_ / 64, B_), 256, 0, stream>>>(
        x, xT16, theta_w, phi_w, g_w, o_w, W16, ow16);
    proj_mfma_kernel<<<dim3(N_ / 64, B_), 256, 0, stream>>>(
        xT16, W16, theta_b, phi_b, g_b, theta_t, phi_t, g2);
    colstats_kernel<<<dim3(N_ / 32, 4, B_), 256, 0, stream>>>(theta_t, phi_t, Z);
    gscale_kernel<<<dim3((B_ * CV_ * N_) / 2048), 256, 0, stream>>>(g2, Z);
    opre_kernel<<<dim3(256), 256, 0, stream>>>(theta_t, phi_t, g2, o_p0, o_p1);
    final_mfma_kernel<<<dim3(N_ / 32, B_), 256, 0, stream>>>(
        o_p0, o_p1, ow16, o_b, gamma, x, out);
}

// Round 9
// 193.701 us; speedup vs baseline: 1.0824x; 1.0347x over previous
//
#include <hip/hip_runtime.h>
#include <math.h>

// Problem constants
#define B_  4
#define C_  256
#define N_  4096
#define CK_ 32
#define CV_ 128

typedef __attribute__((ext_vector_type(8))) short short8;  // 8 bf16 = 4 VGPRs
typedef __attribute__((ext_vector_type(4))) float f32x4;   // MFMA C/D frag
typedef unsigned short u16;
typedef unsigned int   u32;

static constexpr float LOG2E = 1.4426950408889634f;

static __device__ __forceinline__ u16 f2bf(float f) {       // fp32 -> bf16 RNE
    u32 u = __float_as_uint(f);
    u = (u + 0x7FFFu + ((u >> 16) & 1u)) >> 16;
    return (u16)u;
}
static __device__ __forceinline__ float bf2f(u16 h) {
    return __uint_as_float(((u32)h) << 16);
}

// native transcendentals
static __device__ __forceinline__ float fexp2(float x) {
#if __has_builtin(__builtin_amdgcn_exp2f)
    return __builtin_amdgcn_exp2f(x);
#else
    float r; asm("v_exp_f32 %0, %1\n\ts_nop 0" : "=v"(r) : "v"(x)); return r;
#endif
}
static __device__ __forceinline__ float frcp(float x) {
#if __has_builtin(__builtin_amdgcn_rcpf)
    return __builtin_amdgcn_rcpf(x);
#else
    float r; asm("v_rcp_f32 %0, %1\n\ts_nop 0" : "=v"(r) : "v"(x)); return r;
#endif
}
// pack two fp32 -> 2x bf16 (RNE), lo = a, hi = b
static __device__ __forceinline__ u32 cvt_pk_bf16(float a, float b) {
    u32 r; asm("v_cvt_pk_bf16_f32 %0, %1, %2" : "=v"(r) : "v"(a), "v"(b));
    return r;
}

// ---------------------------------------------------------------------------
// Kernel 0: prep = x transpose/convert  +  weight convert (merged).
// ---------------------------------------------------------------------------
__global__ __launch_bounds__(256) void prep_kernel(
    const float* __restrict__ x, u16* __restrict__ xT16,
    const float* __restrict__ theta_w, const float* __restrict__ phi_w,
    const float* __restrict__ g_w,     const float* __restrict__ o_w,
    u16* __restrict__ W16, u16* __restrict__ ow16)
{
    if (blockIdx.x >= N_ / 64) {
        const int base = (((blockIdx.x - N_ / 64) * 16 + blockIdx.y * 4 + blockIdx.z) * 256
                          + threadIdx.x) * 4;
        #pragma unroll
        for (int e0 = 0; e0 < 4; ++e0) {
            const int e = base + e0;
            if (e < 8192)        W16[e] = f2bf(theta_w[e] * LOG2E);
            else if (e < 16384)  W16[e] = f2bf(phi_w[e - 8192]);
            else if (e < 49152)  W16[e] = f2bf(g_w[e - 16384]);
            else                 ow16[e - 49152] = f2bf(o_w[e - 49152]);
        }
        return;
    }

    const int b = blockIdx.z, c0 = blockIdx.y * 64, n0 = blockIdx.x * 64;
    const int t = threadIdx.x;
    __shared__ float tile[64][65];

    const int cr = t >> 4, nc = (t & 15) * 4;
    #pragma unroll
    for (int it = 0; it < 4; ++it) {
        const float4 v = *(const float4*)(x + (size_t)(b * C_ + c0 + cr + it * 16) * N_ + n0 + nc);
        tile[cr + it * 16][nc + 0] = v.x; tile[cr + it * 16][nc + 1] = v.y;
        tile[cr + it * 16][nc + 2] = v.z; tile[cr + it * 16][nc + 3] = v.w;
    }
    __syncthreads();
    const int n = t >> 2, cg = (t & 3) * 16;
    union { u16 us[16]; uint4 u4[2]; } pk;
    #pragma unroll
    for (int e = 0; e < 16; ++e) pk.us[e] = f2bf(tile[cg + e][n]);
    uint4* dst = (uint4*)(xT16 + (size_t)(b * N_ + n0 + n) * C_ + c0 + cg);
    dst[0] = pk.u4[0]; dst[1] = pk.u4[1];
}

// ---------------------------------------------------------------------------
// Kernel 1: projections via MFMA. theta_t/phi_t [n][32] row-major. g stored
// UNSCALED in the PV B-fragment-tiled layout:
//   g2[((b*8 + ctile)*128 + jchunk)*512 + lane*8 + slot]
//   element (c, j): ctile=c>>4, lane=(c&15)+16*((j>>3)&3), slot=j&7,
//   jchunk=j>>5. A wave's PV B-frag load is then one contiguous 1 KB block.
// ---------------------------------------------------------------------------
__global__ __launch_bounds__(256) void proj_mfma_kernel(
    const u16* __restrict__ xT16, const u16* __restrict__ W16,
    const float* __restrict__ theta_b, const float* __restrict__ phi_b,
    const float* __restrict__ g_b,
    u16* __restrict__ theta_t, u16* __restrict__ phi_t, u16* __restrict__ g2)
{
    const int b = blockIdx.y, n0 = blockIdx.x * 64;
    const int w = threadIdx.x >> 6, lane = threadIdx.x & 63;
    const int lr = lane & 15, q = lane >> 4;
    const f32x4 zf = {0.f, 0.f, 0.f, 0.f};

    // ---- theta/phi: wave w owns pixel m-tile w ----
    const u16* xrow = xT16 + (size_t)(b * N_ + n0 + w * 16 + lr) * C_;
    f32x4 acc[4];
    #pragma unroll
    for (int nt = 0; nt < 4; ++nt) acc[nt] = zf;
    for (int ks = 0; ks < 8; ++ks) {
        const short8 aX = *(const short8*)(xrow + ks * 32 + q * 8);
        #pragma unroll
        for (int nt = 0; nt < 4; ++nt) {
            const short8 bW = *(const short8*)(W16 + (size_t)(nt * 16 + lr) * C_ + ks * 32 + q * 8);
            acc[nt] = __builtin_amdgcn_mfma_f32_16x16x32_bf16(aX, bW, acc[nt], 0, 0, 0);
        }
    }
    #pragma unroll
    for (int nt = 0; nt < 4; ++nt) {
        const int o = nt * 16 + lr;
        #pragma unroll
        for (int reg = 0; reg < 4; ++reg) {
            const int n = n0 + w * 16 + q * 4 + reg;
            if (nt < 2)
                theta_t[(size_t)(b * N_ + n) * CK_ + o] = f2bf(acc[nt][reg] + theta_b[o] * LOG2E);
            else
                phi_t[(size_t)(b * N_ + n) * CK_ + (o - 32)] = f2bf(acc[nt][reg] + phi_b[o - 32]);
        }
    }

    // ---- g: wave w owns c m-tiles {2w, 2w+1}; store in frag-tiled layout ----
    #pragma unroll
    for (int mp = 0; mp < 2; ++mp) {
        const int ctile = w * 2 + mp;
        const int crow = ctile * 16;
        f32x4 ag[4];
        #pragma unroll
        for (int nt = 0; nt < 4; ++nt) ag[nt] = zf;
        for (int ks = 0; ks < 8; ++ks) {
            const short8 aW = *(const short8*)(W16 + (size_t)(64 + crow + lr) * C_ + ks * 32 + q * 8);
            #pragma unroll
            for (int nt = 0; nt < 4; ++nt) {
                const short8 bX = *(const short8*)(xT16 + (size_t)(b * N_ + n0 + nt * 16 + lr) * C_ + ks * 32 + q * 8);
                ag[nt] = __builtin_amdgcn_mfma_f32_16x16x32_bf16(aW, bX, ag[nt], 0, 0, 0);
            }
        }
        #pragma unroll
        for (int nt = 0; nt < 4; ++nt) {
            const int jchunk = (n0 >> 5) + (nt >> 1);
            const int lhi = (nt & 1) * 2 + (lr >> 3);
            #pragma unroll
            for (int reg = 0; reg < 4; ++reg) {
                const int c = crow + q * 4 + reg;
                const int lane2 = (q * 4 + reg) + 16 * lhi;
                g2[((size_t)(b * 8 + ctile) * 128 + jchunk) * 512 + lane2 * 8 + (lr & 7)]
                    = f2bf(ag[nt][reg] + g_b[c]);
            }
        }
    }
}

// ---------------------------------------------------------------------------
// Kernel 2: Z[b][j] = sum_i exp2(S[i][j]) via MFMA (R1-proven). Grid (N/32,4,B).
// ---------------------------------------------------------------------------
__global__ __launch_bounds__(256) void colstats_kernel(
    const u16* __restrict__ theta_t, const u16* __restrict__ phi_t,
    float* __restrict__ Z)
{
    const int b  = blockIdx.z;
    const int j0 = blockIdx.x * 32;
    const int istart = blockIdx.y * (N_ / 4);
    const int tid = threadIdx.x;
    const int wave = tid >> 6, lane = tid & 63;
    const int lr = lane & 15, q = lane >> 4;

    const int jW = j0 + (wave & 1) * 16;
    const short8 bF = *(const short8*)(phi_t + (size_t)(b * N_ + jW + lr) * CK_ + q * 8);

    const u16* thp = theta_t + (size_t)b * N_ * CK_;
    const f32x4 zero = {0.f, 0.f, 0.f, 0.f};
    float zacc = 0.f;
    for (int it = istart + (wave >> 1) * 16; it < istart + N_ / 4; it += 32) {
        const short8 aF = *(const short8*)(thp + (size_t)(it + lr) * CK_ + q * 8);
        f32x4 S = __builtin_amdgcn_mfma_f32_16x16x32_bf16(aF, bF, zero, 0, 0, 0);
        zacc += fexp2(S[0]) + fexp2(S[1]) + fexp2(S[2]) + fexp2(S[3]);
    }
    zacc += __shfl_xor(zacc, 16);
    zacc += __shfl_xor(zacc, 32);
    if (lane < 16) atomicAdd(&Z[(size_t)b * N_ + jW + lr], zacc);
}

// ---------------------------------------------------------------------------
// Kernel 3: fold 1/Z into g2 (in place, bf16). R5-proven.
// ---------------------------------------------------------------------------
__global__ __launch_bounds__(256) void gscale_kernel(
    u16* __restrict__ g2, const float* __restrict__ Z)
{
    const size_t idx = ((size_t)blockIdx.x * 256 + threadIdx.x) * 8;
    const int b = (int)(idx >> 19);
    const int j = (int)(((idx >> 9) & 127) * 32 + ((idx >> 7) & 3) * 8);
    uint4 raw = *(const uint4*)(g2 + idx);
    const float4 z0 = *(const float4*)(Z + (size_t)b * N_ + j);
    const float4 z1 = *(const float4*)(Z + (size_t)b * N_ + j + 4);
    const float zz[8] = {z0.x, z0.y, z0.z, z0.w, z1.x, z1.y, z1.z, z1.w};
    u16* pr = (u16*)&raw;
    union { u16 us[8]; uint4 u4; } pk;
    #pragma unroll
    for (int k = 0; k < 8; ++k) pk.us[k] = f2bf(bf2f(pr[k]) * frcp(zz[k]));
    *(uint4*)(g2 + idx) = pk.u4;
}

// ---------------------------------------------------------------------------
// Kernel 4: o_pre partial. Barrier-free, LDS-free. IT=8, CT=2 (R8-proven
// dataflow, 262MB request traffic) + SINGLE DELTA: j split into 4 QUARTERS
// (32 chunks each) -> grid 512 blocks = 2048 waves = 2 waves/SIMD (the
// regime where the line model held; R8's 1/SIMD exposed latency).
// Partials: quarters 0/1 -> fp32 o_p0/o_p1 (R5/R8-proven formulas, byte
// identical); quarters 2/3 -> bf16, aliased into xT16's 8MB (dead after
// proj; stream-ordered). delta(out) from bf16 partials ~2e-4 (<< 0.1 thr).
// ---------------------------------------------------------------------------
__global__ __launch_bounds__(256, 1) void opre_kernel(
    const u16* __restrict__ theta_t, const u16* __restrict__ phi_t,
    const u16* __restrict__ g2,
    float* __restrict__ o_p0, float* __restrict__ o_p1, u16* __restrict__ opb)
{
    const int bx = blockIdx.x;
    const int igg = bx & 7, ch = (bx >> 3) & 3, jq = (bx >> 5) & 3, b = bx >> 7;
    const int w = threadIdx.x >> 6, lane = threadIdx.x & 63;
    const int lr = lane & 15, q = lane >> 4;
    const int i0 = (igg * 4 + w) * 128;       // 8 i-tiles per wave
    const f32x4 zf = {0.f, 0.f, 0.f, 0.f};

    // theta B-frags for 8 i-tiles
    short8 bT[8];
    #pragma unroll
    for (int it = 0; it < 8; ++it)
        bT[it] = *(const short8*)(theta_t + (size_t)(b * N_ + i0 + it * 16 + lr) * CK_ + q * 8);

    // phi A-frag row permutation (row r <-> j = (r>>2)*8 + (r&3))
    const int ja = (lr >> 2) * 8 + (lr & 3);
    const int jstart = jq * (N_ / 4);
    const u16* pA = phi_t + ((size_t)(b * N_) + jstart + ja) * CK_ + q * 8;
    const u16* pG = g2 + ((size_t)(b * 8 + ch * 2) * 128 + jq * 32) * 512 + lane * 8;

    f32x4 acc[8][2];
    #pragma unroll
    for (int it = 0; it < 8; ++it) { acc[it][0] = zf; acc[it][1] = zf; }

    // depth-2 prefetch (named registers, ping-pong)
    short8 A0a = *(const short8*)(pA);
    short8 A1a = *(const short8*)(pA + 4 * CK_);
    short8 G0a = *(const short8*)(pG);
    short8 G1a = *(const short8*)(pG + 128 * 512);
    short8 A0b = *(const short8*)(pA + 32 * CK_);
    short8 A1b = *(const short8*)(pA + 36 * CK_);
    short8 G0b = *(const short8*)(pG + 512);
    short8 G1b = *(const short8*)(pG + 128 * 512 + 512);

#define OPRE_CHUNK(K, A0r, A1r, G0r, G1r)                                          \
    {                                                                               \
        const short8 cA0 = A0r, cA1 = A1r, cG0 = G0r, cG1 = G1r;                    \
        const int kn = ((K) + 2) & 31;                                              \
        A0r = *(const short8*)(pA + (size_t)kn * (32 * CK_));                       \
        A1r = *(const short8*)(pA + (size_t)kn * (32 * CK_) + 4 * CK_);             \
        G0r = *(const short8*)(pG + kn * 512);                                      \
        G1r = *(const short8*)(pG + 128 * 512 + kn * 512);                          \
        _Pragma("unroll")                                                           \
        for (int it = 0; it < 8; ++it) {                                            \
            const f32x4 Sa = __builtin_amdgcn_mfma_f32_16x16x32_bf16(cA0, bT[it], zf, 0, 0, 0); \
            const f32x4 Sb = __builtin_amdgcn_mfma_f32_16x16x32_bf16(cA1, bT[it], zf, 0, 0, 0); \
            union { u32 u[4]; short8 s8; } ef;                                      \
            ef.u[0] = cvt_pk_bf16(fexp2(Sa[0]), fexp2(Sa[1]));                      \
            ef.u[1] = cvt_pk_bf16(fexp2(Sa[2]), fexp2(Sa[3]));                      \
            ef.u[2] = cvt_pk_bf16(fexp2(Sb[0]), fexp2(Sb[1]));                      \
            ef.u[3] = cvt_pk_bf16(fexp2(Sb[2]), fexp2(Sb[3]));                      \
            acc[it][0] = __builtin_amdgcn_mfma_f32_16x16x32_bf16(ef.s8, cG0, acc[it][0], 0, 0, 0); \
            acc[it][1] = __builtin_amdgcn_mfma_f32_16x16x32_bf16(ef.s8, cG1, acc[it][1], 0, 0, 0); \
        }                                                                           \
    }

    for (int k = 0; k < 32; k += 2) {
        OPRE_CHUNK(k,     A0a, A1a, G0a, G1a)
        OPRE_CHUNK(k + 1, A0b, A1b, G0b, G1b)
    }
#undef OPRE_CHUNK

    // store partials in final's B-frag-tiled layout (R5/R8 formulas):
    // [(((b*256 + ntile)*4 + ks)*64 + lane')*8 + slot], ks = ch
    if (jq < 2) {
        float* op = (jq ? o_p1 : o_p0);
        #pragma unroll
        for (int it = 0; it < 8; ++it) {
            const size_t tb = ((size_t)(b * 256 + (i0 >> 4) + it) * 4 + ch) * 512;
            #pragma unroll
            for (int ct = 0; ct < 2; ++ct) {
                #pragma unroll
                for (int reg = 0; reg < 4; ++reg) {
                    const int lane2 = (q * 4 + reg) + 16 * (ct * 2 + (lr >> 3));
                    op[tb + lane2 * 8 + (lr & 7)] = acc[it][ct][reg];
                }
            }
        }
    } else {
        u16* ob = opb + (size_t)(jq - 2) * ((size_t)B_ * N_ * CV_);
        #pragma unroll
        for (int it = 0; it < 8; ++it) {
            const size_t tb = ((size_t)(b * 256 + (i0 >> 4) + it) * 4 + ch) * 512;
            #pragma unroll
            for (int ct = 0; ct < 2; ++ct) {
                #pragma unroll
                for (int reg = 0; reg < 4; ++reg) {
                    const int lane2 = (q * 4 + reg) + 16 * (ct * 2 + (lr >> 3));
                    ob[tb + lane2 * 8 + (lr & 7)] = f2bf(acc[it][ct][reg]);
                }
            }
        }
    }
}

// ---------------------------------------------------------------------------
// Kernel 5: out = x + gamma * (o_w @ (o_p0 + o_p1 + opb0 + opb1) + o_b).
// Partials: 2 fp32 buffers + 2 bf16 buffers (aliased in xT16), all
// frag-tiled -> contiguous loads. Grid (N/32, B) = 512 blocks, 256 thr.
// ---------------------------------------------------------------------------
__global__ __launch_bounds__(256) void final_mfma_kernel(
    const float* __restrict__ o_p0, const float* __restrict__ o_p1,
    const u16* __restrict__ opb,
    const u16* __restrict__ ow16, const float* __restrict__ o_b,
    const float* __restrict__ gamma, const float* __restrict__ x,
    float* __restrict__ out)
{
    const int b = blockIdx.y, n0 = blockIdx.x * 32;
    const int w = threadIdx.x >> 6, lane = threadIdx.x & 63;
    const int lr = lane & 15, q = lane >> 4;
    const f32x4 zf = {0.f, 0.f, 0.f, 0.f};
    const size_t QS = (size_t)B_ * N_ * CV_;

    f32x4 acc[4][2];
    #pragma unroll
    for (int mt = 0; mt < 4; ++mt)
        #pragma unroll
        for (int nt = 0; nt < 2; ++nt) acc[mt][nt] = zf;

    for (int ks = 0; ks < 4; ++ks) {
        short8 bP[2];
        #pragma unroll
        for (int nt = 0; nt < 2; ++nt) {
            const size_t base = (((size_t)(b * 256 + (n0 >> 4) + nt) * 4 + ks) * 64 + lane) * 8;
            const float4 a0 = *(const float4*)(o_p0 + base);
            const float4 a1 = *(const float4*)(o_p0 + base + 4);
            const float4 c0 = *(const float4*)(o_p1 + base);
            const float4 c1 = *(const float4*)(o_p1 + base + 4);
            union { u16 us[8]; uint4 u4; } w2, w3;
            w2.u4 = *(const uint4*)(opb + base);
            w3.u4 = *(const uint4*)(opb + QS + base);
            float s[8] = {a0.x + c0.x, a0.y + c0.y, a0.z + c0.z, a0.w + c0.w,
                          a1.x + c1.x, a1.y + c1.y, a1.z + c1.z, a1.w + c1.w};
            #pragma unroll
            for (int e = 0; e < 8; ++e)
                s[e] += bf2f(w2.us[e]) + bf2f(w3.us[e]);
            union { u32 u[4]; short8 s8; } pk;
            pk.u[0] = cvt_pk_bf16(s[0], s[1]);
            pk.u[1] = cvt_pk_bf16(s[2], s[3]);
            pk.u[2] = cvt_pk_bf16(s[4], s[5]);
            pk.u[3] = cvt_pk_bf16(s[6], s[7]);
            bP[nt] = pk.s8;
        }
        #pragma unroll
        for (int mt = 0; mt < 4; ++mt) {
            const short8 aW = *(const short8*)(ow16 + (size_t)((w * 4 + mt) * 16 + lr) * CV_ + ks * 32 + q * 8);
            #pragma unroll
            for (int nt = 0; nt < 2; ++nt)
                acc[mt][nt] = __builtin_amdgcn_mfma_f32_16x16x32_bf16(aW, bP[nt], acc[mt][nt], 0, 0, 0);
        }
    }

    const float gm = gamma[0];
    #pragma unroll
    for (int mt = 0; mt < 4; ++mt) {
        #pragma unroll
        for (int nt = 0; nt < 2; ++nt) {
            #pragma unroll
            for (int reg = 0; reg < 4; ++reg) {
                const int oc = (w * 4 + mt) * 16 + q * 4 + reg;
                const int n = n0 + nt * 16 + lr;
                const size_t off = (size_t)(b * C_ + oc) * N_ + n;
                out[off] = x[off] + gm * (acc[mt][nt][reg] + o_b[oc]);
            }
        }
    }
}

// ---------------------------------------------------------------------------
extern "C" void kernel_launch(void* const* d_in, const int* in_sizes, int n_in,
                              void* d_out, int out_size, void* d_ws, size_t ws_size,
                              hipStream_t stream)
{
    const float* x       = (const float*)d_in[0];
    const float* theta_w = (const float*)d_in[1];
    const float* theta_b = (const float*)d_in[2];
    const float* phi_w   = (const float*)d_in[3];
    const float* phi_b   = (const float*)d_in[4];
    const float* g_w     = (const float*)d_in[5];
    const float* g_b     = (const float*)d_in[6];
    const float* o_w     = (const float*)d_in[7];
    const float* o_b     = (const float*)d_in[8];
    const float* gamma   = (const float*)d_in[9];
    float* out = (float*)d_out;

    // workspace: xT16 8MB (reused by opre as 2x bf16 partial quarters) |
    //            W16 96KB | ow16 64KB | theta_t 1MB | phi_t 1MB | g2 4MB |
    //            Z 64KB | o_p0 8MB | o_p1 8MB   (~30 MB total)
    u16* xT16    = (u16*)d_ws;
    u16* W16     = xT16 + (size_t)B_ * N_ * C_;
    u16* ow16    = W16 + 192 * C_;
    u16* theta_t = ow16 + C_ * CV_;
    u16* phi_t   = theta_t + (size_t)B_ * N_ * CK_;
    u16* g2      = phi_t + (size_t)B_ * N_ * CK_;
    float* Z     = (float*)(g2 + (size_t)B_ * CV_ * N_);
    float* o_p0  = Z + (size_t)B_ * N_;
    float* o_p1  = o_p0 + (size_t)B_ * N_ * CV_;
    u16* opb     = xT16;   // 2 x 4MB bf16 partial quarters, alias (xT dead after proj)

    hipMemsetAsync(Z, 0, (size_t)B_ * N_ * sizeof(float), stream);

    prep_kernel<<<dim3(N_ / 64 + 5, C_ / 64, B_), 256, 0, stream>>>(
        x, xT16, theta_w, phi_w, g_w, o_w, W16, ow16);
    proj_mfma_kernel<<<dim3(N_ / 64, B_), 256, 0, stream>>>(
        xT16, W16, theta_b, phi_b, g_b, theta_t, phi_t, g2);
    colstats_kernel<<<dim3(N_ / 32, 4, B_), 256, 0, stream>>>(theta_t, phi_t, Z);
    gscale_kernel<<<dim3((B_ * CV_ * N_) / 2048), 256, 0, stream>>>(g2, Z);
    opre_kernel<<<dim3(512), 256, 0, stream>>>(theta_t, phi_t, g2, o_p0, o_p1, opb);
    final_mfma_kernel<<<dim3(N_ / 32, B_), 256, 0, stream>>>(
        o_p0, o_p1, opb, ow16, o_b, gamma, x, out);
}

// Round 10
// 176.982 us; speedup vs baseline: 1.1846x; 1.0945x over previous
//
#include <hip/hip_runtime.h>
#include <math.h>

// Problem constants
#define B_  4
#define C_  256
#define N_  4096
#define CK_ 32
#define CV_ 128

typedef __attribute__((ext_vector_type(8))) short short8;  // 8 bf16 = 4 VGPRs
typedef __attribute__((ext_vector_type(4))) float f32x4;   // MFMA C/D frag
typedef unsigned short u16;
typedef unsigned int   u32;

static constexpr float LOG2E = 1.4426950408889634f;

static __device__ __forceinline__ u16 f2bf(float f) {       // fp32 -> bf16 RNE
    u32 u = __float_as_uint(f);
    u = (u + 0x7FFFu + ((u >> 16) & 1u)) >> 16;
    return (u16)u;
}
static __device__ __forceinline__ float bf2f(u16 h) {
    return __uint_as_float(((u32)h) << 16);
}

// native transcendentals
static __device__ __forceinline__ float fexp2(float x) {
#if __has_builtin(__builtin_amdgcn_exp2f)
    return __builtin_amdgcn_exp2f(x);
#else
    float r; asm("v_exp_f32 %0, %1\n\ts_nop 0" : "=v"(r) : "v"(x)); return r;
#endif
}
static __device__ __forceinline__ float frcp(float x) {
#if __has_builtin(__builtin_amdgcn_rcpf)
    return __builtin_amdgcn_rcpf(x);
#else
    float r; asm("v_rcp_f32 %0, %1\n\ts_nop 0" : "=v"(r) : "v"(x)); return r;
#endif
}
// pack two fp32 -> 2x bf16 (RNE), lo = a, hi = b
static __device__ __forceinline__ u32 cvt_pk_bf16(float a, float b) {
    u32 r; asm("v_cvt_pk_bf16_f32 %0, %1, %2" : "=v"(r) : "v"(a), "v"(b));
    return r;
}

// ---------------------------------------------------------------------------
// Kernel 0: prep = x transpose/convert  +  weight convert (merged).
// ---------------------------------------------------------------------------
__global__ __launch_bounds__(256) void prep_kernel(
    const float* __restrict__ x, u16* __restrict__ xT16,
    const float* __restrict__ theta_w, const float* __restrict__ phi_w,
    const float* __restrict__ g_w,     const float* __restrict__ o_w,
    u16* __restrict__ W16, u16* __restrict__ ow16)
{
    if (blockIdx.x >= N_ / 64) {
        const int base = (((blockIdx.x - N_ / 64) * 16 + blockIdx.y * 4 + blockIdx.z) * 256
                          + threadIdx.x) * 4;
        #pragma unroll
        for (int e0 = 0; e0 < 4; ++e0) {
            const int e = base + e0;
            if (e < 8192)        W16[e] = f2bf(theta_w[e] * LOG2E);
            else if (e < 16384)  W16[e] = f2bf(phi_w[e - 8192]);
            else if (e < 49152)  W16[e] = f2bf(g_w[e - 16384]);
            else                 ow16[e - 49152] = f2bf(o_w[e - 49152]);
        }
        return;
    }

    const int b = blockIdx.z, c0 = blockIdx.y * 64, n0 = blockIdx.x * 64;
    const int t = threadIdx.x;
    __shared__ float tile[64][65];

    const int cr = t >> 4, nc = (t & 15) * 4;
    #pragma unroll
    for (int it = 0; it < 4; ++it) {
        const float4 v = *(const float4*)(x + (size_t)(b * C_ + c0 + cr + it * 16) * N_ + n0 + nc);
        tile[cr + it * 16][nc + 0] = v.x; tile[cr + it * 16][nc + 1] = v.y;
        tile[cr + it * 16][nc + 2] = v.z; tile[cr + it * 16][nc + 3] = v.w;
    }
    __syncthreads();
    const int n = t >> 2, cg = (t & 3) * 16;
    union { u16 us[16]; uint4 u4[2]; } pk;
    #pragma unroll
    for (int e = 0; e < 16; ++e) pk.us[e] = f2bf(tile[cg + e][n]);
    uint4* dst = (uint4*)(xT16 + (size_t)(b * N_ + n0 + n) * C_ + c0 + cg);
    dst[0] = pk.u4[0]; dst[1] = pk.u4[1];
}

// ---------------------------------------------------------------------------
// Kernel 1: projections via MFMA. theta_t/phi_t [n][32] row-major. g stored
// UNSCALED in the PV B-fragment-tiled layout:
//   g2[((b*8 + ctile)*128 + jchunk)*512 + lane*8 + slot]
// ---------------------------------------------------------------------------
__global__ __launch_bounds__(256) void proj_mfma_kernel(
    const u16* __restrict__ xT16, const u16* __restrict__ W16,
    const float* __restrict__ theta_b, const float* __restrict__ phi_b,
    const float* __restrict__ g_b,
    u16* __restrict__ theta_t, u16* __restrict__ phi_t, u16* __restrict__ g2)
{
    const int b = blockIdx.y, n0 = blockIdx.x * 64;
    const int w = threadIdx.x >> 6, lane = threadIdx.x & 63;
    const int lr = lane & 15, q = lane >> 4;
    const f32x4 zf = {0.f, 0.f, 0.f, 0.f};

    // ---- theta/phi: wave w owns pixel m-tile w ----
    const u16* xrow = xT16 + (size_t)(b * N_ + n0 + w * 16 + lr) * C_;
    f32x4 acc[4];
    #pragma unroll
    for (int nt = 0; nt < 4; ++nt) acc[nt] = zf;
    for (int ks = 0; ks < 8; ++ks) {
        const short8 aX = *(const short8*)(xrow + ks * 32 + q * 8);
        #pragma unroll
        for (int nt = 0; nt < 4; ++nt) {
            const short8 bW = *(const short8*)(W16 + (size_t)(nt * 16 + lr) * C_ + ks * 32 + q * 8);
            acc[nt] = __builtin_amdgcn_mfma_f32_16x16x32_bf16(aX, bW, acc[nt], 0, 0, 0);
        }
    }
    #pragma unroll
    for (int nt = 0; nt < 4; ++nt) {
        const int o = nt * 16 + lr;
        #pragma unroll
        for (int reg = 0; reg < 4; ++reg) {
            const int n = n0 + w * 16 + q * 4 + reg;
            if (nt < 2)
                theta_t[(size_t)(b * N_ + n) * CK_ + o] = f2bf(acc[nt][reg] + theta_b[o] * LOG2E);
            else
                phi_t[(size_t)(b * N_ + n) * CK_ + (o - 32)] = f2bf(acc[nt][reg] + phi_b[o - 32]);
        }
    }

    // ---- g: wave w owns c m-tiles {2w, 2w+1}; store in frag-tiled layout ----
    #pragma unroll
    for (int mp = 0; mp < 2; ++mp) {
        const int ctile = w * 2 + mp;
        const int crow = ctile * 16;
        f32x4 ag[4];
        #pragma unroll
        for (int nt = 0; nt < 4; ++nt) ag[nt] = zf;
        for (int ks = 0; ks < 8; ++ks) {
            const short8 aW = *(const short8*)(W16 + (size_t)(64 + crow + lr) * C_ + ks * 32 + q * 8);
            #pragma unroll
            for (int nt = 0; nt < 4; ++nt) {
                const short8 bX = *(const short8*)(xT16 + (size_t)(b * N_ + n0 + nt * 16 + lr) * C_ + ks * 32 + q * 8);
                ag[nt] = __builtin_amdgcn_mfma_f32_16x16x32_bf16(aW, bX, ag[nt], 0, 0, 0);
            }
        }
        #pragma unroll
        for (int nt = 0; nt < 4; ++nt) {
            const int jchunk = (n0 >> 5) + (nt >> 1);
            const int lhi = (nt & 1) * 2 + (lr >> 3);
            #pragma unroll
            for (int reg = 0; reg < 4; ++reg) {
                const int c = crow + q * 4 + reg;
                const int lane2 = (q * 4 + reg) + 16 * lhi;
                g2[((size_t)(b * 8 + ctile) * 128 + jchunk) * 512 + lane2 * 8 + (lr & 7)]
                    = f2bf(ag[nt][reg] + g_b[c]);
            }
        }
    }
}

// ---------------------------------------------------------------------------
// Kernel 2: Z[b][j] = sum_i exp2(S[i][j]) via MFMA (R1-proven). Grid (N/32,4,B).
// ---------------------------------------------------------------------------
__global__ __launch_bounds__(256) void colstats_kernel(
    const u16* __restrict__ theta_t, const u16* __restrict__ phi_t,
    float* __restrict__ Z)
{
    const int b  = blockIdx.z;
    const int j0 = blockIdx.x * 32;
    const int istart = blockIdx.y * (N_ / 4);
    const int tid = threadIdx.x;
    const int wave = tid >> 6, lane = tid & 63;
    const int lr = lane & 15, q = lane >> 4;

    const int jW = j0 + (wave & 1) * 16;
    const short8 bF = *(const short8*)(phi_t + (size_t)(b * N_ + jW + lr) * CK_ + q * 8);

    const u16* thp = theta_t + (size_t)b * N_ * CK_;
    const f32x4 zero = {0.f, 0.f, 0.f, 0.f};
    float zacc = 0.f;
    for (int it = istart + (wave >> 1) * 16; it < istart + N_ / 4; it += 32) {
        const short8 aF = *(const short8*)(thp + (size_t)(it + lr) * CK_ + q * 8);
        f32x4 S = __builtin_amdgcn_mfma_f32_16x16x32_bf16(aF, bF, zero, 0, 0, 0);
        zacc += fexp2(S[0]) + fexp2(S[1]) + fexp2(S[2]) + fexp2(S[3]);
    }
    zacc += __shfl_xor(zacc, 16);
    zacc += __shfl_xor(zacc, 32);
    if (lane < 16) atomicAdd(&Z[(size_t)b * N_ + jW + lr], zacc);
}

// ---------------------------------------------------------------------------
// Kernel 3: fold 1/Z into g2 (in place, bf16). R5-proven.
// ---------------------------------------------------------------------------
__global__ __launch_bounds__(256) void gscale_kernel(
    u16* __restrict__ g2, const float* __restrict__ Z)
{
    const size_t idx = ((size_t)blockIdx.x * 256 + threadIdx.x) * 8;
    const int b = (int)(idx >> 19);
    const int j = (int)(((idx >> 9) & 127) * 32 + ((idx >> 7) & 3) * 8);
    uint4 raw = *(const uint4*)(g2 + idx);
    const float4 z0 = *(const float4*)(Z + (size_t)b * N_ + j);
    const float4 z1 = *(const float4*)(Z + (size_t)b * N_ + j + 4);
    const float zz[8] = {z0.x, z0.y, z0.z, z0.w, z1.x, z1.y, z1.z, z1.w};
    u16* pr = (u16*)&raw;
    union { u16 us[8]; uint4 u4; } pk;
    #pragma unroll
    for (int k = 0; k < 8; ++k) pk.us[k] = f2bf(bf2f(pr[k]) * frcp(zz[k]));
    *(uint4*)(g2 + idx) = pk.u4;
}

// ---------------------------------------------------------------------------
// Kernel 4: o_pre partial. SINGLE DELTA vs R9: E shared across c via LDS.
// Block = 4 waves, same i-range (8 i-tiles, 128 i) and j-quarter; wave w owns
// c-tiles {2w, 2w+1} (block covers full 128 c). Wave w computes S+exp for
// ONLY its 2 i-tiles (E duplication 4x -> 1x; exp was 27us of TRANS issue),
// publishes the 16B/lane E-frags to LDS (linear lane*16; write/read layout
// identical = the proven PV A-frag), 1 barrier/chunk, double-buffered E
// (write(k+2,buf0) separated from read(k,buf0) by sync(k+1) -> race-free).
// Wave count (2048 = 2/SIMD), per-wave loads (2 phi + 2 g /chunk), partial
// buffers (2 fp32 + 2 bf16) and all store formulas byte-identical to R9
// with ch := w.
// ---------------------------------------------------------------------------
__global__ __launch_bounds__(256, 1) void opre_kernel(
    const u16* __restrict__ theta_t, const u16* __restrict__ phi_t,
    const u16* __restrict__ g2,
    float* __restrict__ o_p0, float* __restrict__ o_p1, u16* __restrict__ opb)
{
    const int bx = blockIdx.x;
    const int igg = bx & 31, jq = (bx >> 5) & 3, b = bx >> 7;
    const int w = threadIdx.x >> 6, lane = threadIdx.x & 63;
    const int lr = lane & 15, q = lane >> 4;
    const int i0 = igg * 128;
    const f32x4 zf = {0.f, 0.f, 0.f, 0.f};

    __shared__ u16 El[2][8 * 512];     // [buf][it*512 + lane*8], 2 x 8 KB

    // theta B-frags for MY 2 S-i-tiles (it = 2w, 2w+1)
    const short8 bT0 = *(const short8*)(theta_t + (size_t)(b * N_ + i0 + (2 * w) * 16 + lr) * CK_ + q * 8);
    const short8 bT1 = *(const short8*)(theta_t + (size_t)(b * N_ + i0 + (2 * w + 1) * 16 + lr) * CK_ + q * 8);

    // phi A-frag row permutation (row r <-> j = (r>>2)*8 + (r&3))
    const int ja = (lr >> 2) * 8 + (lr & 3);
    const int jstart = jq * (N_ / 4);
    const u16* pA = phi_t + ((size_t)(b * N_) + jstart + ja) * CK_ + q * 8;
    const u16* pG = g2 + ((size_t)(b * 8 + w * 2) * 128 + jq * 32) * 512 + lane * 8;

    f32x4 acc[8][2];
    #pragma unroll
    for (int it = 0; it < 8; ++it) { acc[it][0] = zf; acc[it][1] = zf; }

    // depth-2 prefetch (named registers, ping-pong) — same addresses as R9
    short8 A0a = *(const short8*)(pA);
    short8 A1a = *(const short8*)(pA + 4 * CK_);
    short8 G0a = *(const short8*)(pG);
    short8 G1a = *(const short8*)(pG + 128 * 512);
    short8 A0b = *(const short8*)(pA + 32 * CK_);
    short8 A1b = *(const short8*)(pA + 36 * CK_);
    short8 G0b = *(const short8*)(pG + 512);
    short8 G1b = *(const short8*)(pG + 128 * 512 + 512);

    u16* const myE0 = &El[0][(2 * w) * 512 + lane * 8];
    u16* const myE1 = &El[0][(2 * w + 1) * 512 + lane * 8];
    const int bufstep = 8 * 512;       // u16 offset between buffers

#define OPRE_CHUNK(K, BUF, A0r, A1r, G0r, G1r)                                     \
    {                                                                               \
        const short8 cA0 = A0r, cA1 = A1r, cG0 = G0r, cG1 = G1r;                    \
        const int kn = ((K) + 2) & 31;                                              \
        A0r = *(const short8*)(pA + (size_t)kn * (32 * CK_));                       \
        A1r = *(const short8*)(pA + (size_t)kn * (32 * CK_) + 4 * CK_);             \
        G0r = *(const short8*)(pG + kn * 512);                                      \
        G1r = *(const short8*)(pG + 128 * 512 + kn * 512);                          \
        /* S + exp for my 2 i-tiles only */                                         \
        const f32x4 Sa0 = __builtin_amdgcn_mfma_f32_16x16x32_bf16(cA0, bT0, zf, 0, 0, 0); \
        const f32x4 Sb0 = __builtin_amdgcn_mfma_f32_16x16x32_bf16(cA1, bT0, zf, 0, 0, 0); \
        const f32x4 Sa1 = __builtin_amdgcn_mfma_f32_16x16x32_bf16(cA0, bT1, zf, 0, 0, 0); \
        const f32x4 Sb1 = __builtin_amdgcn_mfma_f32_16x16x32_bf16(cA1, bT1, zf, 0, 0, 0); \
        union { u32 u[4]; short8 s8; } e0, e1;                                      \
        e0.u[0] = cvt_pk_bf16(fexp2(Sa0[0]), fexp2(Sa0[1]));                        \
        e0.u[1] = cvt_pk_bf16(fexp2(Sa0[2]), fexp2(Sa0[3]));                        \
        e0.u[2] = cvt_pk_bf16(fexp2(Sb0[0]), fexp2(Sb0[1]));                        \
        e0.u[3] = cvt_pk_bf16(fexp2(Sb0[2]), fexp2(Sb0[3]));                        \
        e1.u[0] = cvt_pk_bf16(fexp2(Sa1[0]), fexp2(Sa1[1]));                        \
        e1.u[1] = cvt_pk_bf16(fexp2(Sa1[2]), fexp2(Sa1[3]));                        \
        e1.u[2] = cvt_pk_bf16(fexp2(Sb1[0]), fexp2(Sb1[1]));                        \
        e1.u[3] = cvt_pk_bf16(fexp2(Sb1[2]), fexp2(Sb1[3]));                        \
        *(short8*)(myE0 + (BUF) * bufstep) = e0.s8;                                 \
        *(short8*)(myE1 + (BUF) * bufstep) = e1.s8;                                 \
        __syncthreads();                                                            \
        _Pragma("unroll")                                                           \
        for (int it = 0; it < 8; ++it) {                                            \
            const short8 eF = *(const short8*)(&El[BUF][it * 512 + lane * 8]);      \
            acc[it][0] = __builtin_amdgcn_mfma_f32_16x16x32_bf16(eF, cG0, acc[it][0], 0, 0, 0); \
            acc[it][1] = __builtin_amdgcn_mfma_f32_16x16x32_bf16(eF, cG1, acc[it][1], 0, 0, 0); \
        }                                                                           \
    }

    for (int k = 0; k < 32; k += 2) {
        OPRE_CHUNK(k,     0, A0a, A1a, G0a, G1a)
        OPRE_CHUNK(k + 1, 1, A0b, A1b, G0b, G1b)
    }
#undef OPRE_CHUNK

    // store partials in final's B-frag-tiled layout (R9 formulas, ch := w):
    // [(((b*256 + ntile)*4 + ks)*64 + lane')*8 + slot], ks = w
    if (jq < 2) {
        float* op = (jq ? o_p1 : o_p0);
        #pragma unroll
        for (int it = 0; it < 8; ++it) {
            const size_t tb = ((size_t)(b * 256 + (i0 >> 4) + it) * 4 + w) * 512;
            #pragma unroll
            for (int ct = 0; ct < 2; ++ct) {
                #pragma unroll
                for (int reg = 0; reg < 4; ++reg) {
                    const int lane2 = (q * 4 + reg) + 16 * (ct * 2 + (lr >> 3));
                    op[tb + lane2 * 8 + (lr & 7)] = acc[it][ct][reg];
                }
            }
        }
    } else {
        u16* ob = opb + (size_t)(jq - 2) * ((size_t)B_ * N_ * CV_);
        #pragma unroll
        for (int it = 0; it < 8; ++it) {
            const size_t tb = ((size_t)(b * 256 + (i0 >> 4) + it) * 4 + w) * 512;
            #pragma unroll
            for (int ct = 0; ct < 2; ++ct) {
                #pragma unroll
                for (int reg = 0; reg < 4; ++reg) {
                    const int lane2 = (q * 4 + reg) + 16 * (ct * 2 + (lr >> 3));
                    ob[tb + lane2 * 8 + (lr & 7)] = f2bf(acc[it][ct][reg]);
                }
            }
        }
    }
}

// ---------------------------------------------------------------------------
// Kernel 5: out = x + gamma * (o_w @ (o_p0 + o_p1 + opb0 + opb1) + o_b).
// (R9-proven, unchanged.) Grid (N/32, B) = 512 blocks, 256 thr.
// ---------------------------------------------------------------------------
__global__ __launch_bounds__(256) void final_mfma_kernel(
    const float* __restrict__ o_p0, const float* __restrict__ o_p1,
    const u16* __restrict__ opb,
    const u16* __restrict__ ow16, const float* __restrict__ o_b,
    const float* __restrict__ gamma, const float* __restrict__ x,
    float* __restrict__ out)
{
    const int b = blockIdx.y, n0 = blockIdx.x * 32;
    const int w = threadIdx.x >> 6, lane = threadIdx.x & 63;
    const int lr = lane & 15, q = lane >> 4;
    const f32x4 zf = {0.f, 0.f, 0.f, 0.f};
    const size_t QS = (size_t)B_ * N_ * CV_;

    f32x4 acc[4][2];
    #pragma unroll
    for (int mt = 0; mt < 4; ++mt)
        #pragma unroll
        for (int nt = 0; nt < 2; ++nt) acc[mt][nt] = zf;

    for (int ks = 0; ks < 4; ++ks) {
        short8 bP[2];
        #pragma unroll
        for (int nt = 0; nt < 2; ++nt) {
            const size_t base = (((size_t)(b * 256 + (n0 >> 4) + nt) * 4 + ks) * 64 + lane) * 8;
            const float4 a0 = *(const float4*)(o_p0 + base);
            const float4 a1 = *(const float4*)(o_p0 + base + 4);
            const float4 c0 = *(const float4*)(o_p1 + base);
            const float4 c1 = *(const float4*)(o_p1 + base + 4);
            union { u16 us[8]; uint4 u4; } w2, w3;
            w2.u4 = *(const uint4*)(opb + base);
            w3.u4 = *(const uint4*)(opb + QS + base);
            float s[8] = {a0.x + c0.x, a0.y + c0.y, a0.z + c0.z, a0.w + c0.w,
                          a1.x + c1.x, a1.y + c1.y, a1.z + c1.z, a1.w + c1.w};
            #pragma unroll
            for (int e = 0; e < 8; ++e)
                s[e] += bf2f(w2.us[e]) + bf2f(w3.us[e]);
            union { u32 u[4]; short8 s8; } pk;
            pk.u[0] = cvt_pk_bf16(s[0], s[1]);
            pk.u[1] = cvt_pk_bf16(s[2], s[3]);
            pk.u[2] = cvt_pk_bf16(s[4], s[5]);
            pk.u[3] = cvt_pk_bf16(s[6], s[7]);
            bP[nt] = pk.s8;
        }
        #pragma unroll
        for (int mt = 0; mt < 4; ++mt) {
            const short8 aW = *(const short8*)(ow16 + (size_t)((w * 4 + mt) * 16 + lr) * CV_ + ks * 32 + q * 8);
            #pragma unroll
            for (int nt = 0; nt < 2; ++nt)
                acc[mt][nt] = __builtin_amdgcn_mfma_f32_16x16x32_bf16(aW, bP[nt], acc[mt][nt], 0, 0, 0);
        }
    }

    const float gm = gamma[0];
    #pragma unroll
    for (int mt = 0; mt < 4; ++mt) {
        #pragma unroll
        for (int nt = 0; nt < 2; ++nt) {
            #pragma unroll
            for (int reg = 0; reg < 4; ++reg) {
                const int oc = (w * 4 + mt) * 16 + q * 4 + reg;
                const int n = n0 + nt * 16 + lr;
                const size_t off = (size_t)(b * C_ + oc) * N_ + n;
                out[off] = x[off] + gm * (acc[mt][nt][reg] + o_b[oc]);
            }
        }
    }
}

// ---------------------------------------------------------------------------
extern "C" void kernel_launch(void* const* d_in, const int* in_sizes, int n_in,
                              void* d_out, int out_size, void* d_ws, size_t ws_size,
                              hipStream_t stream)
{
    const float* x       = (const float*)d_in[0];
    const float* theta_w = (const float*)d_in[1];
    const float* theta_b = (const float*)d_in[2];
    const float* phi_w   = (const float*)d_in[3];
    const float* phi_b   = (const float*)d_in[4];
    const float* g_w     = (const float*)d_in[5];
    const float* g_b     = (const float*)d_in[6];
    const float* o_w     = (const float*)d_in[7];
    const float* o_b     = (const float*)d_in[8];
    const float* gamma   = (const float*)d_in[9];
    float* out = (float*)d_out;

    // workspace: xT16 8MB (reused by opre as 2x bf16 partial quarters) |
    //            W16 96KB | ow16 64KB | theta_t 1MB | phi_t 1MB | g2 4MB |
    //            Z 64KB | o_p0 8MB | o_p1 8MB   (~30 MB total)
    u16* xT16    = (u16*)d_ws;
    u16* W16     = xT16 + (size_t)B_ * N_ * C_;
    u16* ow16    = W16 + 192 * C_;
    u16* theta_t = ow16 + C_ * CV_;
    u16* phi_t   = theta_t + (size_t)B_ * N_ * CK_;
    u16* g2      = phi_t + (size_t)B_ * N_ * CK_;
    float* Z     = (float*)(g2 + (size_t)B_ * CV_ * N_);
    float* o_p0  = Z + (size_t)B_ * N_;
    float* o_p1  = o_p0 + (size_t)B_ * N_ * CV_;
    u16* opb     = xT16;   // 2 x 4MB bf16 partial quarters, alias (xT dead after proj)

    hipMemsetAsync(Z, 0, (size_t)B_ * N_ * sizeof(float), stream);

    prep_kernel<<<dim3(N_ / 64 + 5, C_ / 64, B_), 256, 0, stream>>>(
        x, xT16, theta_w, phi_w, g_w, o_w, W16, ow16);
    proj_mfma_kernel<<<dim3(N_ / 64, B_), 256, 0, stream>>>(
        xT16, W16, theta_b, phi_b, g_b, theta_t, phi_t, g2);
    colstats_kernel<<<dim3(N_ / 32, 4, B_), 256, 0, stream>>>(theta_t, phi_t, Z);
    gscale_kernel<<<dim3((B_ * CV_ * N_) / 2048), 256, 0, stream>>>(g2, Z);
    opre_kernel<<<dim3(512), 256, 0, stream>>>(theta_t, phi_t, g2, o_p0, o_p1, opb);
    final_mfma_kernel<<<dim3(N_ / 32, B_), 256, 0, stream>>>(
        o_p0, o_p1, opb, ow16, o_b, gamma, x, out);
}

// Round 11
// 174.542 us; speedup vs baseline: 1.2012x; 1.0140x over previous
//
#include <hip/hip_runtime.h>
#include <math.h>

// Problem constants
#define B_  4
#define C_  256
#define N_  4096
#define CK_ 32
#define CV_ 128

typedef __attribute__((ext_vector_type(8))) short short8;  // 8 bf16 = 4 VGPRs
typedef __attribute__((ext_vector_type(4))) float f32x4;   // MFMA C/D frag
typedef unsigned short u16;
typedef unsigned int   u32;

static constexpr float LOG2E = 1.4426950408889634f;

static __device__ __forceinline__ u16 f2bf(float f) {       // fp32 -> bf16 RNE
    u32 u = __float_as_uint(f);
    u = (u + 0x7FFFu + ((u >> 16) & 1u)) >> 16;
    return (u16)u;
}
static __device__ __forceinline__ float bf2f(u16 h) {
    return __uint_as_float(((u32)h) << 16);
}

// native transcendentals
static __device__ __forceinline__ float fexp2(float x) {
#if __has_builtin(__builtin_amdgcn_exp2f)
    return __builtin_amdgcn_exp2f(x);
#else
    float r; asm("v_exp_f32 %0, %1\n\ts_nop 0" : "=v"(r) : "v"(x)); return r;
#endif
}
static __device__ __forceinline__ float frcp(float x) {
#if __has_builtin(__builtin_amdgcn_rcpf)
    return __builtin_amdgcn_rcpf(x);
#else
    float r; asm("v_rcp_f32 %0, %1\n\ts_nop 0" : "=v"(r) : "v"(x)); return r;
#endif
}
// pack two fp32 -> 2x bf16 (RNE), lo = a, hi = b
static __device__ __forceinline__ u32 cvt_pk_bf16(float a, float b) {
    u32 r; asm("v_cvt_pk_bf16_f32 %0, %1, %2" : "=v"(r) : "v"(a), "v"(b));
    return r;
}

// ---------------------------------------------------------------------------
// Kernel 0: prep = x transpose/convert  +  weight convert (merged).
// ---------------------------------------------------------------------------
__global__ __launch_bounds__(256) void prep_kernel(
    const float* __restrict__ x, u16* __restrict__ xT16,
    const float* __restrict__ theta_w, const float* __restrict__ phi_w,
    const float* __restrict__ g_w,     const float* __restrict__ o_w,
    u16* __restrict__ W16, u16* __restrict__ ow16)
{
    if (blockIdx.x >= N_ / 64) {
        const int base = (((blockIdx.x - N_ / 64) * 16 + blockIdx.y * 4 + blockIdx.z) * 256
                          + threadIdx.x) * 4;
        #pragma unroll
        for (int e0 = 0; e0 < 4; ++e0) {
            const int e = base + e0;
            if (e < 8192)        W16[e] = f2bf(theta_w[e] * LOG2E);
            else if (e < 16384)  W16[e] = f2bf(phi_w[e - 8192]);
            else if (e < 49152)  W16[e] = f2bf(g_w[e - 16384]);
            else                 ow16[e - 49152] = f2bf(o_w[e - 49152]);
        }
        return;
    }

    const int b = blockIdx.z, c0 = blockIdx.y * 64, n0 = blockIdx.x * 64;
    const int t = threadIdx.x;
    __shared__ float tile[64][65];

    const int cr = t >> 4, nc = (t & 15) * 4;
    #pragma unroll
    for (int it = 0; it < 4; ++it) {
        const float4 v = *(const float4*)(x + (size_t)(b * C_ + c0 + cr + it * 16) * N_ + n0 + nc);
        tile[cr + it * 16][nc + 0] = v.x; tile[cr + it * 16][nc + 1] = v.y;
        tile[cr + it * 16][nc + 2] = v.z; tile[cr + it * 16][nc + 3] = v.w;
    }
    __syncthreads();
    const int n = t >> 2, cg = (t & 3) * 16;
    union { u16 us[16]; uint4 u4[2]; } pk;
    #pragma unroll
    for (int e = 0; e < 16; ++e) pk.us[e] = f2bf(tile[cg + e][n]);
    uint4* dst = (uint4*)(xT16 + (size_t)(b * N_ + n0 + n) * C_ + c0 + cg);
    dst[0] = pk.u4[0]; dst[1] = pk.u4[1];
}

// ---------------------------------------------------------------------------
// Kernel 1: projections via MFMA. theta_t/phi_t [n][32] row-major. g stored
// UNSCALED in the PV B-fragment-tiled layout:
//   g2[((b*8 + ctile)*128 + jchunk)*512 + lane*8 + slot]
// ---------------------------------------------------------------------------
__global__ __launch_bounds__(256) void proj_mfma_kernel(
    const u16* __restrict__ xT16, const u16* __restrict__ W16,
    const float* __restrict__ theta_b, const float* __restrict__ phi_b,
    const float* __restrict__ g_b,
    u16* __restrict__ theta_t, u16* __restrict__ phi_t, u16* __restrict__ g2)
{
    const int b = blockIdx.y, n0 = blockIdx.x * 64;
    const int w = threadIdx.x >> 6, lane = threadIdx.x & 63;
    const int lr = lane & 15, q = lane >> 4;
    const f32x4 zf = {0.f, 0.f, 0.f, 0.f};

    // ---- theta/phi: wave w owns pixel m-tile w ----
    const u16* xrow = xT16 + (size_t)(b * N_ + n0 + w * 16 + lr) * C_;
    f32x4 acc[4];
    #pragma unroll
    for (int nt = 0; nt < 4; ++nt) acc[nt] = zf;
    for (int ks = 0; ks < 8; ++ks) {
        const short8 aX = *(const short8*)(xrow + ks * 32 + q * 8);
        #pragma unroll
        for (int nt = 0; nt < 4; ++nt) {
            const short8 bW = *(const short8*)(W16 + (size_t)(nt * 16 + lr) * C_ + ks * 32 + q * 8);
            acc[nt] = __builtin_amdgcn_mfma_f32_16x16x32_bf16(aX, bW, acc[nt], 0, 0, 0);
        }
    }
    #pragma unroll
    for (int nt = 0; nt < 4; ++nt) {
        const int o = nt * 16 + lr;
        #pragma unroll
        for (int reg = 0; reg < 4; ++reg) {
            const int n = n0 + w * 16 + q * 4 + reg;
            if (nt < 2)
                theta_t[(size_t)(b * N_ + n) * CK_ + o] = f2bf(acc[nt][reg] + theta_b[o] * LOG2E);
            else
                phi_t[(size_t)(b * N_ + n) * CK_ + (o - 32)] = f2bf(acc[nt][reg] + phi_b[o - 32]);
        }
    }

    // ---- g: wave w owns c m-tiles {2w, 2w+1}; store in frag-tiled layout ----
    #pragma unroll
    for (int mp = 0; mp < 2; ++mp) {
        const int ctile = w * 2 + mp;
        const int crow = ctile * 16;
        f32x4 ag[4];
        #pragma unroll
        for (int nt = 0; nt < 4; ++nt) ag[nt] = zf;
        for (int ks = 0; ks < 8; ++ks) {
            const short8 aW = *(const short8*)(W16 + (size_t)(64 + crow + lr) * C_ + ks * 32 + q * 8);
            #pragma unroll
            for (int nt = 0; nt < 4; ++nt) {
                const short8 bX = *(const short8*)(xT16 + (size_t)(b * N_ + n0 + nt * 16 + lr) * C_ + ks * 32 + q * 8);
                ag[nt] = __builtin_amdgcn_mfma_f32_16x16x32_bf16(aW, bX, ag[nt], 0, 0, 0);
            }
        }
        #pragma unroll
        for (int nt = 0; nt < 4; ++nt) {
            const int jchunk = (n0 >> 5) + (nt >> 1);
            const int lhi = (nt & 1) * 2 + (lr >> 3);
            #pragma unroll
            for (int reg = 0; reg < 4; ++reg) {
                const int c = crow + q * 4 + reg;
                const int lane2 = (q * 4 + reg) + 16 * lhi;
                g2[((size_t)(b * 8 + ctile) * 128 + jchunk) * 512 + lane2 * 8 + (lr & 7)]
                    = f2bf(ag[nt][reg] + g_b[c]);
            }
        }
    }
}

// ---------------------------------------------------------------------------
// Kernel 2: Z[b][j] = sum_i exp2(S[i][j]) via MFMA. SINGLE DELTA vs R10:
// 4 phi-frags per wave (64 j) -> each theta A-load feeds 4 MFMAs (theta
// request traffic 268 -> 67 MB). Grid (N/64, 4, B) = 1024 blocks, 4096
// waves = 4/SIMD. Lane lr holds column j = j0 + jt*16 + lr; shfl_xor
// 16/32 reduces q-groups over i; waves 0-3 at stride 64 cover the
// i-quarter exactly.
// ---------------------------------------------------------------------------
__global__ __launch_bounds__(256) void colstats_kernel(
    const u16* __restrict__ theta_t, const u16* __restrict__ phi_t,
    float* __restrict__ Z)
{
    const int b  = blockIdx.z;
    const int j0 = blockIdx.x * 64;
    const int istart = blockIdx.y * (N_ / 4);
    const int tid = threadIdx.x;
    const int w = tid >> 6, lane = tid & 63;
    const int lr = lane & 15, q = lane >> 4;

    short8 bF[4];
    #pragma unroll
    for (int jt = 0; jt < 4; ++jt)
        bF[jt] = *(const short8*)(phi_t + (size_t)(b * N_ + j0 + jt * 16 + lr) * CK_ + q * 8);

    const u16* thp = theta_t + (size_t)b * N_ * CK_;
    const f32x4 zero = {0.f, 0.f, 0.f, 0.f};
    float za0 = 0.f, za1 = 0.f, za2 = 0.f, za3 = 0.f;
    for (int i = istart + w * 16; i < istart + N_ / 4; i += 64) {
        const short8 aF = *(const short8*)(thp + (size_t)(i + lr) * CK_ + q * 8);
        f32x4 S0 = __builtin_amdgcn_mfma_f32_16x16x32_bf16(aF, bF[0], zero, 0, 0, 0);
        f32x4 S1 = __builtin_amdgcn_mfma_f32_16x16x32_bf16(aF, bF[1], zero, 0, 0, 0);
        f32x4 S2 = __builtin_amdgcn_mfma_f32_16x16x32_bf16(aF, bF[2], zero, 0, 0, 0);
        f32x4 S3 = __builtin_amdgcn_mfma_f32_16x16x32_bf16(aF, bF[3], zero, 0, 0, 0);
        za0 += fexp2(S0[0]) + fexp2(S0[1]) + fexp2(S0[2]) + fexp2(S0[3]);
        za1 += fexp2(S1[0]) + fexp2(S1[1]) + fexp2(S1[2]) + fexp2(S1[3]);
        za2 += fexp2(S2[0]) + fexp2(S2[1]) + fexp2(S2[2]) + fexp2(S2[3]);
        za3 += fexp2(S3[0]) + fexp2(S3[1]) + fexp2(S3[2]) + fexp2(S3[3]);
    }
    za0 += __shfl_xor(za0, 16); za0 += __shfl_xor(za0, 32);
    za1 += __shfl_xor(za1, 16); za1 += __shfl_xor(za1, 32);
    za2 += __shfl_xor(za2, 16); za2 += __shfl_xor(za2, 32);
    za3 += __shfl_xor(za3, 16); za3 += __shfl_xor(za3, 32);
    if (lane < 16) {
        atomicAdd(&Z[(size_t)b * N_ + j0 + 0  + lr], za0);
        atomicAdd(&Z[(size_t)b * N_ + j0 + 16 + lr], za1);
        atomicAdd(&Z[(size_t)b * N_ + j0 + 32 + lr], za2);
        atomicAdd(&Z[(size_t)b * N_ + j0 + 48 + lr], za3);
    }
}

// ---------------------------------------------------------------------------
// Kernel 3: fold 1/Z into g2 (in place, bf16). R5-proven.
// ---------------------------------------------------------------------------
__global__ __launch_bounds__(256) void gscale_kernel(
    u16* __restrict__ g2, const float* __restrict__ Z)
{
    const size_t idx = ((size_t)blockIdx.x * 256 + threadIdx.x) * 8;
    const int b = (int)(idx >> 19);
    const int j = (int)(((idx >> 9) & 127) * 32 + ((idx >> 7) & 3) * 8);
    uint4 raw = *(const uint4*)(g2 + idx);
    const float4 z0 = *(const float4*)(Z + (size_t)b * N_ + j);
    const float4 z1 = *(const float4*)(Z + (size_t)b * N_ + j + 4);
    const float zz[8] = {z0.x, z0.y, z0.z, z0.w, z1.x, z1.y, z1.z, z1.w};
    u16* pr = (u16*)&raw;
    union { u16 us[8]; uint4 u4; } pk;
    #pragma unroll
    for (int k = 0; k < 8; ++k) pk.us[k] = f2bf(bf2f(pr[k]) * frcp(zz[k]));
    *(uint4*)(g2 + idx) = pk.u4;
}

// ---------------------------------------------------------------------------
// Kernel 4: o_pre partial (R10-proven: LDS E-sharing across c). Unchanged.
// ---------------------------------------------------------------------------
__global__ __launch_bounds__(256, 1) void opre_kernel(
    const u16* __restrict__ theta_t, const u16* __restrict__ phi_t,
    const u16* __restrict__ g2,
    float* __restrict__ o_p0, float* __restrict__ o_p1, u16* __restrict__ opb)
{
    const int bx = blockIdx.x;
    const int igg = bx & 31, jq = (bx >> 5) & 3, b = bx >> 7;
    const int w = threadIdx.x >> 6, lane = threadIdx.x & 63;
    const int lr = lane & 15, q = lane >> 4;
    const int i0 = igg * 128;
    const f32x4 zf = {0.f, 0.f, 0.f, 0.f};

    __shared__ u16 El[2][8 * 512];     // [buf][it*512 + lane*8], 2 x 8 KB

    // theta B-frags for MY 2 S-i-tiles (it = 2w, 2w+1)
    const short8 bT0 = *(const short8*)(theta_t + (size_t)(b * N_ + i0 + (2 * w) * 16 + lr) * CK_ + q * 8);
    const short8 bT1 = *(const short8*)(theta_t + (size_t)(b * N_ + i0 + (2 * w + 1) * 16 + lr) * CK_ + q * 8);

    // phi A-frag row permutation (row r <-> j = (r>>2)*8 + (r&3))
    const int ja = (lr >> 2) * 8 + (lr & 3);
    const int jstart = jq * (N_ / 4);
    const u16* pA = phi_t + ((size_t)(b * N_) + jstart + ja) * CK_ + q * 8;
    const u16* pG = g2 + ((size_t)(b * 8 + w * 2) * 128 + jq * 32) * 512 + lane * 8;

    f32x4 acc[8][2];
    #pragma unroll
    for (int it = 0; it < 8; ++it) { acc[it][0] = zf; acc[it][1] = zf; }

    // depth-2 prefetch (named registers, ping-pong)
    short8 A0a = *(const short8*)(pA);
    short8 A1a = *(const short8*)(pA + 4 * CK_);
    short8 G0a = *(const short8*)(pG);
    short8 G1a = *(const short8*)(pG + 128 * 512);
    short8 A0b = *(const short8*)(pA + 32 * CK_);
    short8 A1b = *(const short8*)(pA + 36 * CK_);
    short8 G0b = *(const short8*)(pG + 512);
    short8 G1b = *(const short8*)(pG + 128 * 512 + 512);

    u16* const myE0 = &El[0][(2 * w) * 512 + lane * 8];
    u16* const myE1 = &El[0][(2 * w + 1) * 512 + lane * 8];
    const int bufstep = 8 * 512;       // u16 offset between buffers

#define OPRE_CHUNK(K, BUF, A0r, A1r, G0r, G1r)                                     \
    {                                                                               \
        const short8 cA0 = A0r, cA1 = A1r, cG0 = G0r, cG1 = G1r;                    \
        const int kn = ((K) + 2) & 31;                                              \
        A0r = *(const short8*)(pA + (size_t)kn * (32 * CK_));                       \
        A1r = *(const short8*)(pA + (size_t)kn * (32 * CK_) + 4 * CK_);             \
        G0r = *(const short8*)(pG + kn * 512);                                      \
        G1r = *(const short8*)(pG + 128 * 512 + kn * 512);                          \
        /* S + exp for my 2 i-tiles only */                                         \
        const f32x4 Sa0 = __builtin_amdgcn_mfma_f32_16x16x32_bf16(cA0, bT0, zf, 0, 0, 0); \
        const f32x4 Sb0 = __builtin_amdgcn_mfma_f32_16x16x32_bf16(cA1, bT0, zf, 0, 0, 0); \
        const f32x4 Sa1 = __builtin_amdgcn_mfma_f32_16x16x32_bf16(cA0, bT1, zf, 0, 0, 0); \
        const f32x4 Sb1 = __builtin_amdgcn_mfma_f32_16x16x32_bf16(cA1, bT1, zf, 0, 0, 0); \
        union { u32 u[4]; short8 s8; } e0, e1;                                      \
        e0.u[0] = cvt_pk_bf16(fexp2(Sa0[0]), fexp2(Sa0[1]));                        \
        e0.u[1] = cvt_pk_bf16(fexp2(Sa0[2]), fexp2(Sa0[3]));                        \
        e0.u[2] = cvt_pk_bf16(fexp2(Sb0[0]), fexp2(Sb0[1]));                        \
        e0.u[3] = cvt_pk_bf16(fexp2(Sb0[2]), fexp2(Sb0[3]));                        \
        e1.u[0] = cvt_pk_bf16(fexp2(Sa1[0]), fexp2(Sa1[1]));                        \
        e1.u[1] = cvt_pk_bf16(fexp2(Sa1[2]), fexp2(Sa1[3]));                        \
        e1.u[2] = cvt_pk_bf16(fexp2(Sb1[0]), fexp2(Sb1[1]));                        \
        e1.u[3] = cvt_pk_bf16(fexp2(Sb1[2]), fexp2(Sb1[3]));                        \
        *(short8*)(myE0 + (BUF) * bufstep) = e0.s8;                                 \
        *(short8*)(myE1 + (BUF) * bufstep) = e1.s8;                                 \
        __syncthreads();                                                            \
        _Pragma("unroll")                                                           \
        for (int it = 0; it < 8; ++it) {                                            \
            const short8 eF = *(const short8*)(&El[BUF][it * 512 + lane * 8]);      \
            acc[it][0] = __builtin_amdgcn_mfma_f32_16x16x32_bf16(eF, cG0, acc[it][0], 0, 0, 0); \
            acc[it][1] = __builtin_amdgcn_mfma_f32_16x16x32_bf16(eF, cG1, acc[it][1], 0, 0, 0); \
        }                                                                           \
    }

    for (int k = 0; k < 32; k += 2) {
        OPRE_CHUNK(k,     0, A0a, A1a, G0a, G1a)
        OPRE_CHUNK(k + 1, 1, A0b, A1b, G0b, G1b)
    }
#undef OPRE_CHUNK

    // store partials in final's B-frag-tiled layout (R9 formulas, ch := w):
    // [(((b*256 + ntile)*4 + ks)*64 + lane')*8 + slot], ks = w
    if (jq < 2) {
        float* op = (jq ? o_p1 : o_p0);
        #pragma unroll
        for (int it = 0; it < 8; ++it) {
            const size_t tb = ((size_t)(b * 256 + (i0 >> 4) + it) * 4 + w) * 512;
            #pragma unroll
            for (int ct = 0; ct < 2; ++ct) {
                #pragma unroll
                for (int reg = 0; reg < 4; ++reg) {
                    const int lane2 = (q * 4 + reg) + 16 * (ct * 2 + (lr >> 3));
                    op[tb + lane2 * 8 + (lr & 7)] = acc[it][ct][reg];
                }
            }
        }
    } else {
        u16* ob = opb + (size_t)(jq - 2) * ((size_t)B_ * N_ * CV_);
        #pragma unroll
        for (int it = 0; it < 8; ++it) {
            const size_t tb = ((size_t)(b * 256 + (i0 >> 4) + it) * 4 + w) * 512;
            #pragma unroll
            for (int ct = 0; ct < 2; ++ct) {
                #pragma unroll
                for (int reg = 0; reg < 4; ++reg) {
                    const int lane2 = (q * 4 + reg) + 16 * (ct * 2 + (lr >> 3));
                    ob[tb + lane2 * 8 + (lr & 7)] = f2bf(acc[it][ct][reg]);
                }
            }
        }
    }
}

// ---------------------------------------------------------------------------
// Kernel 5: out = x + gamma * (o_w @ (o_p0 + o_p1 + opb0 + opb1) + o_b).
// (R9-proven, unchanged.) Grid (N/32, B) = 512 blocks, 256 thr.
// ---------------------------------------------------------------------------
__global__ __launch_bounds__(256) void final_mfma_kernel(
    const float* __restrict__ o_p0, const float* __restrict__ o_p1,
    const u16* __restrict__ opb,
    const u16* __restrict__ ow16, const float* __restrict__ o_b,
    const float* __restrict__ gamma, const float* __restrict__ x,
    float* __restrict__ out)
{
    const int b = blockIdx.y, n0 = blockIdx.x * 32;
    const int w = threadIdx.x >> 6, lane = threadIdx.x & 63;
    const int lr = lane & 15, q = lane >> 4;
    const f32x4 zf = {0.f, 0.f, 0.f, 0.f};
    const size_t QS = (size_t)B_ * N_ * CV_;

    f32x4 acc[4][2];
    #pragma unroll
    for (int mt = 0; mt < 4; ++mt)
        #pragma unroll
        for (int nt = 0; nt < 2; ++nt) acc[mt][nt] = zf;

    for (int ks = 0; ks < 4; ++ks) {
        short8 bP[2];
        #pragma unroll
        for (int nt = 0; nt < 2; ++nt) {
            const size_t base = (((size_t)(b * 256 + (n0 >> 4) + nt) * 4 + ks) * 64 + lane) * 8;
            const float4 a0 = *(const float4*)(o_p0 + base);
            const float4 a1 = *(const float4*)(o_p0 + base + 4);
            const float4 c0 = *(const float4*)(o_p1 + base);
            const float4 c1 = *(const float4*)(o_p1 + base + 4);
            union { u16 us[8]; uint4 u4; } w2, w3;
            w2.u4 = *(const uint4*)(opb + base);
            w3.u4 = *(const uint4*)(opb + QS + base);
            float s[8] = {a0.x + c0.x, a0.y + c0.y, a0.z + c0.z, a0.w + c0.w,
                          a1.x + c1.x, a1.y + c1.y, a1.z + c1.z, a1.w + c1.w};
            #pragma unroll
            for (int e = 0; e < 8; ++e)
                s[e] += bf2f(w2.us[e]) + bf2f(w3.us[e]);
            union { u32 u[4]; short8 s8; } pk;
            pk.u[0] = cvt_pk_bf16(s[0], s[1]);
            pk.u[1] = cvt_pk_bf16(s[2], s[3]);
            pk.u[2] = cvt_pk_bf16(s[4], s[5]);
            pk.u[3] = cvt_pk_bf16(s[6], s[7]);
            bP[nt] = pk.s8;
        }
        #pragma unroll
        for (int mt = 0; mt < 4; ++mt) {
            const short8 aW = *(const short8*)(ow16 + (size_t)((w * 4 + mt) * 16 + lr) * CV_ + ks * 32 + q * 8);
            #pragma unroll
            for (int nt = 0; nt < 2; ++nt)
                acc[mt][nt] = __builtin_amdgcn_mfma_f32_16x16x32_bf16(aW, bP[nt], acc[mt][nt], 0, 0, 0);
        }
    }

    const float gm = gamma[0];
    #pragma unroll
    for (int mt = 0; mt < 4; ++mt) {
        #pragma unroll
        for (int nt = 0; nt < 2; ++nt) {
            #pragma unroll
            for (int reg = 0; reg < 4; ++reg) {
                const int oc = (w * 4 + mt) * 16 + q * 4 + reg;
                const int n = n0 + nt * 16 + lr;
                const size_t off = (size_t)(b * C_ + oc) * N_ + n;
                out[off] = x[off] + gm * (acc[mt][nt][reg] + o_b[oc]);
            }
        }
    }
}

// ---------------------------------------------------------------------------
extern "C" void kernel_launch(void* const* d_in, const int* in_sizes, int n_in,
                              void* d_out, int out_size, void* d_ws, size_t ws_size,
                              hipStream_t stream)
{
    const float* x       = (const float*)d_in[0];
    const float* theta_w = (const float*)d_in[1];
    const float* theta_b = (const float*)d_in[2];
    const float* phi_w   = (const float*)d_in[3];
    const float* phi_b   = (const float*)d_in[4];
    const float* g_w     = (const float*)d_in[5];
    const float* g_b     = (const float*)d_in[6];
    const float* o_w     = (const float*)d_in[7];
    const float* o_b     = (const float*)d_in[8];
    const float* gamma   = (const float*)d_in[9];
    float* out = (float*)d_out;

    // workspace: xT16 8MB (reused by opre as 2x bf16 partial quarters) |
    //            W16 96KB | ow16 64KB | theta_t 1MB | phi_t 1MB | g2 4MB |
    //            Z 64KB | o_p0 8MB | o_p1 8MB   (~30 MB total)
    u16* xT16    = (u16*)d_ws;
    u16* W16     = xT16 + (size_t)B_ * N_ * C_;
    u16* ow16    = W16 + 192 * C_;
    u16* theta_t = ow16 + C_ * CV_;
    u16* phi_t   = theta_t + (size_t)B_ * N_ * CK_;
    u16* g2      = phi_t + (size_t)B_ * N_ * CK_;
    float* Z     = (float*)(g2 + (size_t)B_ * CV_ * N_);
    float* o_p0  = Z + (size_t)B_ * N_;
    float* o_p1  = o_p0 + (size_t)B_ * N_ * CV_;
    u16* opb     = xT16;   // 2 x 4MB bf16 partial quarters, alias (xT dead after proj)

    hipMemsetAsync(Z, 0, (size_t)B_ * N_ * sizeof(float), stream);

    prep_kernel<<<dim3(N_ / 64 + 5, C_ / 64, B_), 256, 0, stream>>>(
        x, xT16, theta_w, phi_w, g_w, o_w, W16, ow16);
    proj_mfma_kernel<<<dim3(N_ / 64, B_), 256, 0, stream>>>(
        xT16, W16, theta_b, phi_b, g_b, theta_t, phi_t, g2);
    colstats_kernel<<<dim3(N_ / 64, 4, B_), 256, 0, stream>>>(theta_t, phi_t, Z);
    gscale_kernel<<<dim3((B_ * CV_ * N_) / 2048), 256, 0, stream>>>(g2, Z);
    opre_kernel<<<dim3(512), 256, 0, stream>>>(theta_t, phi_t, g2, o_p0, o_p1, opb);
    final_mfma_kernel<<<dim3(N_ / 32, B_), 256, 0, stream>>>(
        o_p0, o_p1, opb, ow16, o_b, gamma, x, out);
}

// Round 12
// 172.186 us; speedup vs baseline: 1.2176x; 1.0137x over previous
//
#include <hip/hip_runtime.h>
#include <math.h>

// Problem constants
#define B_  4
#define C_  256
#define N_  4096
#define CK_ 32
#define CV_ 128

typedef __attribute__((ext_vector_type(8))) short short8;  // 8 bf16 = 4 VGPRs
typedef __attribute__((ext_vector_type(4))) float f32x4;   // MFMA C/D frag
typedef unsigned short u16;
typedef unsigned int   u32;

static constexpr float LOG2E = 1.4426950408889634f;

static __device__ __forceinline__ u16 f2bf(float f) {       // fp32 -> bf16 RNE
    u32 u = __float_as_uint(f);
    u = (u + 0x7FFFu + ((u >> 16) & 1u)) >> 16;
    return (u16)u;
}
static __device__ __forceinline__ float bf2f(u16 h) {
    return __uint_as_float(((u32)h) << 16);
}

// native transcendentals
static __device__ __forceinline__ float fexp2(float x) {
#if __has_builtin(__builtin_amdgcn_exp2f)
    return __builtin_amdgcn_exp2f(x);
#else
    float r; asm("v_exp_f32 %0, %1\n\ts_nop 0" : "=v"(r) : "v"(x)); return r;
#endif
}
static __device__ __forceinline__ float frcp(float x) {
#if __has_builtin(__builtin_amdgcn_rcpf)
    return __builtin_amdgcn_rcpf(x);
#else
    float r; asm("v_rcp_f32 %0, %1\n\ts_nop 0" : "=v"(r) : "v"(x)); return r;
#endif
}
// pack two fp32 -> 2x bf16 (RNE), lo = a, hi = b
static __device__ __forceinline__ u32 cvt_pk_bf16(float a, float b) {
    u32 r; asm("v_cvt_pk_bf16_f32 %0, %1, %2" : "=v"(r) : "v"(a), "v"(b));
    return r;
}

// ---------------------------------------------------------------------------
// Kernel 0: prep = x transpose/convert  +  weight convert (merged).
// ---------------------------------------------------------------------------
__global__ __launch_bounds__(256) void prep_kernel(
    const float* __restrict__ x, u16* __restrict__ xT16,
    const float* __restrict__ theta_w, const float* __restrict__ phi_w,
    const float* __restrict__ g_w,     const float* __restrict__ o_w,
    u16* __restrict__ W16, u16* __restrict__ ow16)
{
    if (blockIdx.x >= N_ / 64) {
        const int base = (((blockIdx.x - N_ / 64) * 16 + blockIdx.y * 4 + blockIdx.z) * 256
                          + threadIdx.x) * 4;
        #pragma unroll
        for (int e0 = 0; e0 < 4; ++e0) {
            const int e = base + e0;
            if (e < 8192)        W16[e] = f2bf(theta_w[e] * LOG2E);
            else if (e < 16384)  W16[e] = f2bf(phi_w[e - 8192]);
            else if (e < 49152)  W16[e] = f2bf(g_w[e - 16384]);
            else                 ow16[e - 49152] = f2bf(o_w[e - 49152]);
        }
        return;
    }

    const int b = blockIdx.z, c0 = blockIdx.y * 64, n0 = blockIdx.x * 64;
    const int t = threadIdx.x;
    __shared__ float tile[64][65];

    const int cr = t >> 4, nc = (t & 15) * 4;
    #pragma unroll
    for (int it = 0; it < 4; ++it) {
        const float4 v = *(const float4*)(x + (size_t)(b * C_ + c0 + cr + it * 16) * N_ + n0 + nc);
        tile[cr + it * 16][nc + 0] = v.x; tile[cr + it * 16][nc + 1] = v.y;
        tile[cr + it * 16][nc + 2] = v.z; tile[cr + it * 16][nc + 3] = v.w;
    }
    __syncthreads();
    const int n = t >> 2, cg = (t & 3) * 16;
    union { u16 us[16]; uint4 u4[2]; } pk;
    #pragma unroll
    for (int e = 0; e < 16; ++e) pk.us[e] = f2bf(tile[cg + e][n]);
    uint4* dst = (uint4*)(xT16 + (size_t)(b * N_ + n0 + n) * C_ + c0 + cg);
    dst[0] = pk.u4[0]; dst[1] = pk.u4[1];
}

// ---------------------------------------------------------------------------
// Kernel 1: projections via MFMA. theta_t/phi_t [n][32] row-major. g stored
// UNSCALED in the PV B-fragment-tiled layout:
//   g2[((b*8 + ctile)*128 + jchunk)*512 + lane*8 + slot]
// ---------------------------------------------------------------------------
__global__ __launch_bounds__(256) void proj_mfma_kernel(
    const u16* __restrict__ xT16, const u16* __restrict__ W16,
    const float* __restrict__ theta_b, const float* __restrict__ phi_b,
    const float* __restrict__ g_b,
    u16* __restrict__ theta_t, u16* __restrict__ phi_t, u16* __restrict__ g2)
{
    const int b = blockIdx.y, n0 = blockIdx.x * 64;
    const int w = threadIdx.x >> 6, lane = threadIdx.x & 63;
    const int lr = lane & 15, q = lane >> 4;
    const f32x4 zf = {0.f, 0.f, 0.f, 0.f};

    // ---- theta/phi: wave w owns pixel m-tile w ----
    const u16* xrow = xT16 + (size_t)(b * N_ + n0 + w * 16 + lr) * C_;
    f32x4 acc[4];
    #pragma unroll
    for (int nt = 0; nt < 4; ++nt) acc[nt] = zf;
    for (int ks = 0; ks < 8; ++ks) {
        const short8 aX = *(const short8*)(xrow + ks * 32 + q * 8);
        #pragma unroll
        for (int nt = 0; nt < 4; ++nt) {
            const short8 bW = *(const short8*)(W16 + (size_t)(nt * 16 + lr) * C_ + ks * 32 + q * 8);
            acc[nt] = __builtin_amdgcn_mfma_f32_16x16x32_bf16(aX, bW, acc[nt], 0, 0, 0);
        }
    }
    #pragma unroll
    for (int nt = 0; nt < 4; ++nt) {
        const int o = nt * 16 + lr;
        #pragma unroll
        for (int reg = 0; reg < 4; ++reg) {
            const int n = n0 + w * 16 + q * 4 + reg;
            if (nt < 2)
                theta_t[(size_t)(b * N_ + n) * CK_ + o] = f2bf(acc[nt][reg] + theta_b[o] * LOG2E);
            else
                phi_t[(size_t)(b * N_ + n) * CK_ + (o - 32)] = f2bf(acc[nt][reg] + phi_b[o - 32]);
        }
    }

    // ---- g: wave w owns c m-tiles {2w, 2w+1}; store in frag-tiled layout ----
    #pragma unroll
    for (int mp = 0; mp < 2; ++mp) {
        const int ctile = w * 2 + mp;
        const int crow = ctile * 16;
        f32x4 ag[4];
        #pragma unroll
        for (int nt = 0; nt < 4; ++nt) ag[nt] = zf;
        for (int ks = 0; ks < 8; ++ks) {
            const short8 aW = *(const short8*)(W16 + (size_t)(64 + crow + lr) * C_ + ks * 32 + q * 8);
            #pragma unroll
            for (int nt = 0; nt < 4; ++nt) {
                const short8 bX = *(const short8*)(xT16 + (size_t)(b * N_ + n0 + nt * 16 + lr) * C_ + ks * 32 + q * 8);
                ag[nt] = __builtin_amdgcn_mfma_f32_16x16x32_bf16(aW, bX, ag[nt], 0, 0, 0);
            }
        }
        #pragma unroll
        for (int nt = 0; nt < 4; ++nt) {
            const int jchunk = (n0 >> 5) + (nt >> 1);
            const int lhi = (nt & 1) * 2 + (lr >> 3);
            #pragma unroll
            for (int reg = 0; reg < 4; ++reg) {
                const int c = crow + q * 4 + reg;
                const int lane2 = (q * 4 + reg) + 16 * lhi;
                g2[((size_t)(b * 8 + ctile) * 128 + jchunk) * 512 + lane2 * 8 + (lr & 7)]
                    = f2bf(ag[nt][reg] + g_b[c]);
            }
        }
    }
}

// ---------------------------------------------------------------------------
// Kernel 2: Z[b][j] = sum_i exp2(S[i][j]) via MFMA, 4 phi-frags/wave
// (R11-proven). Grid (N/64, 4, B).
// ---------------------------------------------------------------------------
__global__ __launch_bounds__(256) void colstats_kernel(
    const u16* __restrict__ theta_t, const u16* __restrict__ phi_t,
    float* __restrict__ Z)
{
    const int b  = blockIdx.z;
    const int j0 = blockIdx.x * 64;
    const int istart = blockIdx.y * (N_ / 4);
    const int tid = threadIdx.x;
    const int w = tid >> 6, lane = tid & 63;
    const int lr = lane & 15, q = lane >> 4;

    short8 bF[4];
    #pragma unroll
    for (int jt = 0; jt < 4; ++jt)
        bF[jt] = *(const short8*)(phi_t + (size_t)(b * N_ + j0 + jt * 16 + lr) * CK_ + q * 8);

    const u16* thp = theta_t + (size_t)b * N_ * CK_;
    const f32x4 zero = {0.f, 0.f, 0.f, 0.f};
    float za0 = 0.f, za1 = 0.f, za2 = 0.f, za3 = 0.f;
    for (int i = istart + w * 16; i < istart + N_ / 4; i += 64) {
        const short8 aF = *(const short8*)(thp + (size_t)(i + lr) * CK_ + q * 8);
        f32x4 S0 = __builtin_amdgcn_mfma_f32_16x16x32_bf16(aF, bF[0], zero, 0, 0, 0);
        f32x4 S1 = __builtin_amdgcn_mfma_f32_16x16x32_bf16(aF, bF[1], zero, 0, 0, 0);
        f32x4 S2 = __builtin_amdgcn_mfma_f32_16x16x32_bf16(aF, bF[2], zero, 0, 0, 0);
        f32x4 S3 = __builtin_amdgcn_mfma_f32_16x16x32_bf16(aF, bF[3], zero, 0, 0, 0);
        za0 += fexp2(S0[0]) + fexp2(S0[1]) + fexp2(S0[2]) + fexp2(S0[3]);
        za1 += fexp2(S1[0]) + fexp2(S1[1]) + fexp2(S1[2]) + fexp2(S1[3]);
        za2 += fexp2(S2[0]) + fexp2(S2[1]) + fexp2(S2[2]) + fexp2(S2[3]);
        za3 += fexp2(S3[0]) + fexp2(S3[1]) + fexp2(S3[2]) + fexp2(S3[3]);
    }
    za0 += __shfl_xor(za0, 16); za0 += __shfl_xor(za0, 32);
    za1 += __shfl_xor(za1, 16); za1 += __shfl_xor(za1, 32);
    za2 += __shfl_xor(za2, 16); za2 += __shfl_xor(za2, 32);
    za3 += __shfl_xor(za3, 16); za3 += __shfl_xor(za3, 32);
    if (lane < 16) {
        atomicAdd(&Z[(size_t)b * N_ + j0 + 0  + lr], za0);
        atomicAdd(&Z[(size_t)b * N_ + j0 + 16 + lr], za1);
        atomicAdd(&Z[(size_t)b * N_ + j0 + 32 + lr], za2);
        atomicAdd(&Z[(size_t)b * N_ + j0 + 48 + lr], za3);
    }
}

// ---------------------------------------------------------------------------
// Kernel 3: fold 1/Z into g2 (in place, bf16). R5-proven.
// ---------------------------------------------------------------------------
__global__ __launch_bounds__(256) void gscale_kernel(
    u16* __restrict__ g2, const float* __restrict__ Z)
{
    const size_t idx = ((size_t)blockIdx.x * 256 + threadIdx.x) * 8;
    const int b = (int)(idx >> 19);
    const int j = (int)(((idx >> 9) & 127) * 32 + ((idx >> 7) & 3) * 8);
    uint4 raw = *(const uint4*)(g2 + idx);
    const float4 z0 = *(const float4*)(Z + (size_t)b * N_ + j);
    const float4 z1 = *(const float4*)(Z + (size_t)b * N_ + j + 4);
    const float zz[8] = {z0.x, z0.y, z0.z, z0.w, z1.x, z1.y, z1.z, z1.w};
    u16* pr = (u16*)&raw;
    union { u16 us[8]; uint4 u4; } pk;
    #pragma unroll
    for (int k = 0; k < 8; ++k) pk.us[k] = f2bf(bf2f(pr[k]) * frcp(zz[k]));
    *(uint4*)(g2 + idx) = pk.u4;
}

// ---------------------------------------------------------------------------
// Kernel 4: o_pre partial (R10/R11 structure). SINGLE DELTA: phi A-frags
// loaded by wave 0 ONLY and shared via a 2-slot LDS frag buffer Ph
// (lane-linear 16B — same conflict-free pattern as El). Removes the 4x
// phi-load duplication: request lines/chunk/block 256 -> 160 (-37%).
// Sync discipline (verified against the existing 1 barrier/chunk):
//   prologue: w0 loads phi(0),phi(1); writes phi(0)->Ph[0]; syncthreads.
//   chunk k: w0 writes phi(k+1)->Ph[(k+1)&1] (regs loaded at k-1),
//            issues load phi(k+2); ALL waves read phi(k) from Ph[k&1]
//            (written pre-sync(k-1), read post-sync(k-1));
//            slot-reuse write(k+2)->Ph[k&1] at chunk k+1 is separated
//            from reads(k) by sync(k). E buffer unchanged (R10-proven).
// ---------------------------------------------------------------------------
__global__ __launch_bounds__(256, 1) void opre_kernel(
    const u16* __restrict__ theta_t, const u16* __restrict__ phi_t,
    const u16* __restrict__ g2,
    float* __restrict__ o_p0, float* __restrict__ o_p1, u16* __restrict__ opb)
{
    const int bx = blockIdx.x;
    const int igg = bx & 31, jq = (bx >> 5) & 3, b = bx >> 7;
    const int w = threadIdx.x >> 6, lane = threadIdx.x & 63;
    const int lr = lane & 15, q = lane >> 4;
    const int i0 = igg * 128;
    const f32x4 zf = {0.f, 0.f, 0.f, 0.f};

    __shared__ u16 El[2][8 * 512];     // [buf][it*512 + lane*8], 2 x 8 KB
    __shared__ u16 Ph[2][1024];        // [slot][frag(2) x lane*8], 2 x 2 KB

    // theta B-frags for MY 2 S-i-tiles (it = 2w, 2w+1)
    const short8 bT0 = *(const short8*)(theta_t + (size_t)(b * N_ + i0 + (2 * w) * 16 + lr) * CK_ + q * 8);
    const short8 bT1 = *(const short8*)(theta_t + (size_t)(b * N_ + i0 + (2 * w + 1) * 16 + lr) * CK_ + q * 8);

    // phi A-frag row permutation (row r <-> j = (r>>2)*8 + (r&3))
    const int ja = (lr >> 2) * 8 + (lr & 3);
    const int jstart = jq * (N_ / 4);
    const u16* pA = phi_t + ((size_t)(b * N_) + jstart + ja) * CK_ + q * 8;
    const u16* pG = g2 + ((size_t)(b * 8 + w * 2) * 128 + jq * 32) * 512 + lane * 8;

    f32x4 acc[8][2];
    #pragma unroll
    for (int it = 0; it < 8; ++it) { acc[it][0] = zf; acc[it][1] = zf; }

    // phi prefetch: wave 0 only (shared via Ph). g prefetch: all waves.
    short8 A0a = {}, A1a = {}, A0b = {}, A1b = {};
    if (w == 0) {
        A0a = *(const short8*)(pA);
        A1a = *(const short8*)(pA + 4 * CK_);
        A0b = *(const short8*)(pA + 32 * CK_);
        A1b = *(const short8*)(pA + 36 * CK_);
        *(short8*)(&Ph[0][lane * 8])       = A0a;    // publish phi(0)
        *(short8*)(&Ph[0][512 + lane * 8]) = A1a;
    }
    short8 G0a = *(const short8*)(pG);
    short8 G1a = *(const short8*)(pG + 128 * 512);
    short8 G0b = *(const short8*)(pG + 512);
    short8 G1b = *(const short8*)(pG + 128 * 512 + 512);
    __syncthreads();

    u16* const myE0 = &El[0][(2 * w) * 512 + lane * 8];
    u16* const myE1 = &El[0][(2 * w + 1) * 512 + lane * 8];
    const int bufstep = 8 * 512;       // u16 offset between E buffers

// AW* = regs holding phi(K+1) (publish now); AL* = regs to refill with phi(K+2)
#define OPRE_CHUNK(K, BUF, AW0, AW1, AL0, AL1, G0r, G1r)                           \
    {                                                                               \
        const int kn = ((K) + 2) & 31;                                              \
        if (w == 0) {                                                               \
            *(short8*)(&Ph[(BUF) ^ 1][lane * 8])       = AW0;                       \
            *(short8*)(&Ph[(BUF) ^ 1][512 + lane * 8]) = AW1;                       \
            AL0 = *(const short8*)(pA + (size_t)kn * (32 * CK_));                   \
            AL1 = *(const short8*)(pA + (size_t)kn * (32 * CK_) + 4 * CK_);         \
        }                                                                           \
        const short8 cG0 = G0r, cG1 = G1r;                                          \
        G0r = *(const short8*)(pG + kn * 512);                                      \
        G1r = *(const short8*)(pG + 128 * 512 + kn * 512);                          \
        const short8 cA0 = *(const short8*)(&Ph[BUF][lane * 8]);                    \
        const short8 cA1 = *(const short8*)(&Ph[BUF][512 + lane * 8]);              \
        /* S + exp for my 2 i-tiles only */                                         \
        const f32x4 Sa0 = __builtin_amdgcn_mfma_f32_16x16x32_bf16(cA0, bT0, zf, 0, 0, 0); \
        const f32x4 Sb0 = __builtin_amdgcn_mfma_f32_16x16x32_bf16(cA1, bT0, zf, 0, 0, 0); \
        const f32x4 Sa1 = __builtin_amdgcn_mfma_f32_16x16x32_bf16(cA0, bT1, zf, 0, 0, 0); \
        const f32x4 Sb1 = __builtin_amdgcn_mfma_f32_16x16x32_bf16(cA1, bT1, zf, 0, 0, 0); \
        union { u32 u[4]; short8 s8; } e0, e1;                                      \
        e0.u[0] = cvt_pk_bf16(fexp2(Sa0[0]), fexp2(Sa0[1]));                        \
        e0.u[1] = cvt_pk_bf16(fexp2(Sa0[2]), fexp2(Sa0[3]));                        \
        e0.u[2] = cvt_pk_bf16(fexp2(Sb0[0]), fexp2(Sb0[1]));                        \
        e0.u[3] = cvt_pk_bf16(fexp2(Sb0[2]), fexp2(Sb0[3]));                        \
        e1.u[0] = cvt_pk_bf16(fexp2(Sa1[0]), fexp2(Sa1[1]));                        \
        e1.u[1] = cvt_pk_bf16(fexp2(Sa1[2]), fexp2(Sa1[3]));                        \
        e1.u[2] = cvt_pk_bf16(fexp2(Sb1[0]), fexp2(Sb1[1]));                        \
        e1.u[3] = cvt_pk_bf16(fexp2(Sb1[2]), fexp2(Sb1[3]));                        \
        *(short8*)(myE0 + (BUF) * bufstep) = e0.s8;                                 \
        *(short8*)(myE1 + (BUF) * bufstep) = e1.s8;                                 \
        __syncthreads();                                                            \
        _Pragma("unroll")                                                           \
        for (int it = 0; it < 8; ++it) {                                            \
            const short8 eF = *(const short8*)(&El[BUF][it * 512 + lane * 8]);      \
            acc[it][0] = __builtin_amdgcn_mfma_f32_16x16x32_bf16(eF, cG0, acc[it][0], 0, 0, 0); \
            acc[it][1] = __builtin_amdgcn_mfma_f32_16x16x32_bf16(eF, cG1, acc[it][1], 0, 0, 0); \
        }                                                                           \
    }

    for (int k = 0; k < 32; k += 2) {
        OPRE_CHUNK(k,     0, A0b, A1b, A0a, A1a, G0a, G1a)   // publish phi(k+1)=b, refill a
        OPRE_CHUNK(k + 1, 1, A0a, A1a, A0b, A1b, G0b, G1b)   // publish phi(k+2)=a, refill b
    }
#undef OPRE_CHUNK

    // store partials in final's B-frag-tiled layout (R9 formulas, ch := w):
    // [(((b*256 + ntile)*4 + ks)*64 + lane')*8 + slot], ks = w
    if (jq < 2) {
        float* op = (jq ? o_p1 : o_p0);
        #pragma unroll
        for (int it = 0; it < 8; ++it) {
            const size_t tb = ((size_t)(b * 256 + (i0 >> 4) + it) * 4 + w) * 512;
            #pragma unroll
            for (int ct = 0; ct < 2; ++ct) {
                #pragma unroll
                for (int reg = 0; reg < 4; ++reg) {
                    const int lane2 = (q * 4 + reg) + 16 * (ct * 2 + (lr >> 3));
                    op[tb + lane2 * 8 + (lr & 7)] = acc[it][ct][reg];
                }
            }
        }
    } else {
        u16* ob = opb + (size_t)(jq - 2) * ((size_t)B_ * N_ * CV_);
        #pragma unroll
        for (int it = 0; it < 8; ++it) {
            const size_t tb = ((size_t)(b * 256 + (i0 >> 4) + it) * 4 + w) * 512;
            #pragma unroll
            for (int ct = 0; ct < 2; ++ct) {
                #pragma unroll
                for (int reg = 0; reg < 4; ++reg) {
                    const int lane2 = (q * 4 + reg) + 16 * (ct * 2 + (lr >> 3));
                    ob[tb + lane2 * 8 + (lr & 7)] = f2bf(acc[it][ct][reg]);
                }
            }
        }
    }
}

// ---------------------------------------------------------------------------
// Kernel 5: out = x + gamma * (o_w @ (o_p0 + o_p1 + opb0 + opb1) + o_b).
// (R9-proven, unchanged.) Grid (N/32, B) = 512 blocks, 256 thr.
// ---------------------------------------------------------------------------
__global__ __launch_bounds__(256) void final_mfma_kernel(
    const float* __restrict__ o_p0, const float* __restrict__ o_p1,
    const u16* __restrict__ opb,
    const u16* __restrict__ ow16, const float* __restrict__ o_b,
    const float* __restrict__ gamma, const float* __restrict__ x,
    float* __restrict__ out)
{
    const int b = blockIdx.y, n0 = blockIdx.x * 32;
    const int w = threadIdx.x >> 6, lane = threadIdx.x & 63;
    const int lr = lane & 15, q = lane >> 4;
    const f32x4 zf = {0.f, 0.f, 0.f, 0.f};
    const size_t QS = (size_t)B_ * N_ * CV_;

    f32x4 acc[4][2];
    #pragma unroll
    for (int mt = 0; mt < 4; ++mt)
        #pragma unroll
        for (int nt = 0; nt < 2; ++nt) acc[mt][nt] = zf;

    for (int ks = 0; ks < 4; ++ks) {
        short8 bP[2];
        #pragma unroll
        for (int nt = 0; nt < 2; ++nt) {
            const size_t base = (((size_t)(b * 256 + (n0 >> 4) + nt) * 4 + ks) * 64 + lane) * 8;
            const float4 a0 = *(const float4*)(o_p0 + base);
            const float4 a1 = *(const float4*)(o_p0 + base + 4);
            const float4 c0 = *(const float4*)(o_p1 + base);
            const float4 c1 = *(const float4*)(o_p1 + base + 4);
            union { u16 us[8]; uint4 u4; } w2, w3;
            w2.u4 = *(const uint4*)(opb + base);
            w3.u4 = *(const uint4*)(opb + QS + base);
            float s[8] = {a0.x + c0.x, a0.y + c0.y, a0.z + c0.z, a0.w + c0.w,
                          a1.x + c1.x, a1.y + c1.y, a1.z + c1.z, a1.w + c1.w};
            #pragma unroll
            for (int e = 0; e < 8; ++e)
                s[e] += bf2f(w2.us[e]) + bf2f(w3.us[e]);
            union { u32 u[4]; short8 s8; } pk;
            pk.u[0] = cvt_pk_bf16(s[0], s[1]);
            pk.u[1] = cvt_pk_bf16(s[2], s[3]);
            pk.u[2] = cvt_pk_bf16(s[4], s[5]);
            pk.u[3] = cvt_pk_bf16(s[6], s[7]);
            bP[nt] = pk.s8;
        }
        #pragma unroll
        for (int mt = 0; mt < 4; ++mt) {
            const short8 aW = *(const short8*)(ow16 + (size_t)((w * 4 + mt) * 16 + lr) * CV_ + ks * 32 + q * 8);
            #pragma unroll
            for (int nt = 0; nt < 2; ++nt)
                acc[mt][nt] = __builtin_amdgcn_mfma_f32_16x16x32_bf16(aW, bP[nt], acc[mt][nt], 0, 0, 0);
        }
    }

    const float gm = gamma[0];
    #pragma unroll
    for (int mt = 0; mt < 4; ++mt) {
        #pragma unroll
        for (int nt = 0; nt < 2; ++nt) {
            #pragma unroll
            for (int reg = 0; reg < 4; ++reg) {
                const int oc = (w * 4 + mt) * 16 + q * 4 + reg;
                const int n = n0 + nt * 16 + lr;
                const size_t off = (size_t)(b * C_ + oc) * N_ + n;
                out[off] = x[off] + gm * (acc[mt][nt][reg] + o_b[oc]);
            }
        }
    }
}

// ---------------------------------------------------------------------------
extern "C" void kernel_launch(void* const* d_in, const int* in_sizes, int n_in,
                              void* d_out, int out_size, void* d_ws, size_t ws_size,
                              hipStream_t stream)
{
    const float* x       = (const float*)d_in[0];
    const float* theta_w = (const float*)d_in[1];
    const float* theta_b = (const float*)d_in[2];
    const float* phi_w   = (const float*)d_in[3];
    const float* phi_b   = (const float*)d_in[4];
    const float* g_w     = (const float*)d_in[5];
    const float* g_b     = (const float*)d_in[6];
    const float* o_w     = (const float*)d_in[7];
    const float* o_b     = (const float*)d_in[8];
    const float* gamma   = (const float*)d_in[9];
    float* out = (float*)d_out;

    // workspace: xT16 8MB (reused by opre as 2x bf16 partial quarters) |
    //            W16 96KB | ow16 64KB | theta_t 1MB | phi_t 1MB | g2 4MB |
    //            Z 64KB | o_p0 8MB | o_p1 8MB   (~30 MB total)
    u16* xT16    = (u16*)d_ws;
    u16* W16     = xT16 + (size_t)B_ * N_ * C_;
    u16* ow16    = W16 + 192 * C_;
    u16* theta_t = ow16 + C_ * CV_;
    u16* phi_t   = theta_t + (size_t)B_ * N_ * CK_;
    u16* g2      = phi_t + (size_t)B_ * N_ * CK_;
    float* Z     = (float*)(g2 + (size_t)B_ * CV_ * N_);
    float* o_p0  = Z + (size_t)B_ * N_;
    float* o_p1  = o_p0 + (size_t)B_ * N_ * CV_;
    u16* opb     = xT16;   // 2 x 4MB bf16 partial quarters, alias (xT dead after proj)

    hipMemsetAsync(Z, 0, (size_t)B_ * N_ * sizeof(float), stream);

    prep_kernel<<<dim3(N_ / 64 + 5, C_ / 64, B_), 256, 0, stream>>>(
        x, xT16, theta_w, phi_w, g_w, o_w, W16, ow16);
    proj_mfma_kernel<<<dim3(N_ / 64, B_), 256, 0, stream>>>(
        xT16, W16, theta_b, phi_b, g_b, theta_t, phi_t, g2);
    colstats_kernel<<<dim3(N_ / 64, 4, B_), 256, 0, stream>>>(theta_t, phi_t, Z);
    gscale_kernel<<<dim3((B_ * CV_ * N_) / 2048), 256, 0, stream>>>(g2, Z);
    opre_kernel<<<dim3(512), 256, 0, stream>>>(theta_t, phi_t, g2, o_p0, o_p1, opb);
    final_mfma_kernel<<<dim3(N_ / 32, B_), 256, 0, stream>>>(
        o_p0, o_p1, opb, ow16, o_b, gamma, x, out);
}